// Round 2
// baseline (765.351 us; speedup 1.0000x reference)
//
#include <hip/hip_runtime.h>
#include <math.h>

#define B_ 4
#define T_ 2048
#define C_ 1024
#define H_ 16
#define D_ 64
#define BT_ (B_*T_)

typedef __bf16 bf16x8 __attribute__((ext_vector_type(8)));
typedef float f32x4 __attribute__((ext_vector_type(4)));
typedef unsigned short u16x8 __attribute__((ext_vector_type(8)));

__device__ __forceinline__ unsigned short f2bf(float f) {
    unsigned u = __builtin_bit_cast(unsigned, f);
    u += 0x7FFFu + ((u >> 16) & 1u);
    return (unsigned short)(u >> 16);
}
__device__ __forceinline__ float bf2f(unsigned short h) {
    unsigned u = ((unsigned)h) << 16;
    return __builtin_bit_cast(float, u);
}
__device__ __forceinline__ void split2(float f, unsigned short& h, unsigned short& l) {
    h = f2bf(f);
    l = f2bf(f - bf2f(h));
}
__device__ __forceinline__ f32x4 zero4() { f32x4 z = {0.f, 0.f, 0.f, 0.f}; return z; }

// ---------------------------------------------------------------------------
// Kernel 1: fused QKV projection, split-bf16 for q,k.  grid(64, 16), block 256.
// BK=32.  q,k stored as (hi,lo) bf16 pairs; v stored plain bf16.
// ---------------------------------------------------------------------------
__global__ __launch_bounds__(256) void qkv_kernel(
    const float* __restrict__ x, const float* __restrict__ Wq,
    const float* __restrict__ Wk, const float* __restrict__ Wv,
    unsigned short* __restrict__ qhi, unsigned short* __restrict__ qlo,
    unsigned short* __restrict__ khi, unsigned short* __restrict__ klo,
    unsigned short* __restrict__ vb)
{
    const int tile = blockIdx.x;
    const int h = blockIdx.y;
    const int row0 = tile * 128;
    const int tid = threadIdx.x;
    const int wid = tid >> 6;
    const int lane = tid & 63;
    const int l15 = lane & 15;
    const int lhi = lane >> 4;

    __shared__ unsigned short Xh[128][36], Xl[128][36];       // X tile hi/lo
    __shared__ unsigned short Wsh[2][64][36], Wsl[2][64][36]; // Wq,Wk ^T hi/lo
    __shared__ unsigned short Wsv[64][36];                    // Wv ^T

    f32x4 acc[3][2][4];
    #pragma unroll
    for (int m = 0; m < 3; m++)
        #pragma unroll
        for (int i = 0; i < 2; i++)
            #pragma unroll
            for (int j = 0; j < 4; j++) acc[m][i][j] = zero4();

    const float* Wqk[2] = { Wq + (size_t)h * C_ * D_, Wk + (size_t)h * C_ * D_ };
    const float* Wvm = Wv + (size_t)h * C_ * D_;

    for (int k0 = 0; k0 < C_; k0 += 32) {
        __syncthreads();
        // stage X[128][32] fp32 -> hi/lo bf16
        {
            int r = tid >> 1;
            int cb = (tid & 1) * 16;
            const float* src = x + (size_t)(row0 + r) * C_ + k0 + cb;
            #pragma unroll
            for (int i = 0; i < 4; i++) {
                f32x4 v = *reinterpret_cast<const f32x4*>(src + i * 4);
                #pragma unroll
                for (int j = 0; j < 4; j++) {
                    unsigned short hh, ll;
                    split2(v[j], hh, ll);
                    Xh[r][cb + i * 4 + j] = hh;
                    Xl[r][cb + i * 4 + j] = ll;
                }
            }
        }
        // stage Wq,Wk transposed hi/lo; Wv transposed hi only
        {
            int cl = tid >> 3;             // 0..31 (k index)
            int d0 = (tid & 7) * 8;        // 0..56
            #pragma unroll
            for (int m = 0; m < 2; m++) {
                const float* src = Wqk[m] + (size_t)(k0 + cl) * D_ + d0;
                #pragma unroll
                for (int i = 0; i < 8; i++) {
                    unsigned short hh, ll;
                    split2(src[i], hh, ll);
                    Wsh[m][d0 + i][cl] = hh;
                    Wsl[m][d0 + i][cl] = ll;
                }
            }
            const float* src = Wvm + (size_t)(k0 + cl) * D_ + d0;
            #pragma unroll
            for (int i = 0; i < 8; i++)
                Wsv[d0 + i][cl] = f2bf(src[i]);
        }
        __syncthreads();

        bf16x8 ah[2], al[2];
        #pragma unroll
        for (int mt = 0; mt < 2; mt++) {
            int r = wid * 32 + mt * 16 + l15;
            ah[mt] = *reinterpret_cast<const bf16x8*>(&Xh[r][lhi * 8]);
            al[mt] = *reinterpret_cast<const bf16x8*>(&Xl[r][lhi * 8]);
        }
        #pragma unroll
        for (int m = 0; m < 2; m++) {
            #pragma unroll
            for (int nt = 0; nt < 4; nt++) {
                bf16x8 bh = *reinterpret_cast<const bf16x8*>(&Wsh[m][nt * 16 + l15][lhi * 8]);
                bf16x8 bl = *reinterpret_cast<const bf16x8*>(&Wsl[m][nt * 16 + l15][lhi * 8]);
                #pragma unroll
                for (int mt = 0; mt < 2; mt++) {
                    acc[m][mt][nt] = __builtin_amdgcn_mfma_f32_16x16x32_bf16(ah[mt], bh, acc[m][mt][nt], 0, 0, 0);
                    acc[m][mt][nt] = __builtin_amdgcn_mfma_f32_16x16x32_bf16(ah[mt], bl, acc[m][mt][nt], 0, 0, 0);
                    acc[m][mt][nt] = __builtin_amdgcn_mfma_f32_16x16x32_bf16(al[mt], bh, acc[m][mt][nt], 0, 0, 0);
                }
            }
        }
        #pragma unroll
        for (int nt = 0; nt < 4; nt++) {
            bf16x8 bv = *reinterpret_cast<const bf16x8*>(&Wsv[nt * 16 + l15][lhi * 8]);
            #pragma unroll
            for (int mt = 0; mt < 2; mt++)
                acc[2][mt][nt] = __builtin_amdgcn_mfma_f32_16x16x32_bf16(ah[mt], bv, acc[2][mt][nt], 0, 0, 0);
        }
    }

    #pragma unroll
    for (int mt = 0; mt < 2; mt++) {
        #pragma unroll
        for (int nt = 0; nt < 4; nt++) {
            #pragma unroll
            for (int r2 = 0; r2 < 4; r2++) {
                int grow = row0 + wid * 32 + mt * 16 + lhi * 4 + r2;
                int b = grow >> 11;
                int t = grow & (T_ - 1);
                int d = nt * 16 + l15;
                size_t idx = (((size_t)(b * H_ + h)) * T_ + t) * D_ + d;
                unsigned short hh, ll;
                split2(acc[0][mt][nt][r2], hh, ll);
                qhi[idx] = hh; qlo[idx] = ll;
                split2(acc[1][mt][nt][r2], hh, ll);
                khi[idx] = hh; klo[idx] = ll;
                vb[idx] = f2bf(acc[2][mt][nt][r2]);
            }
        }
    }
}

// ---------------------------------------------------------------------------
// Kernel 2: causal flash attention with split-bf16 QK^T.  grid(16, 64), block 256.
// ---------------------------------------------------------------------------
__global__ __launch_bounds__(256) void flash_kernel(
    const unsigned short* __restrict__ qhi, const unsigned short* __restrict__ qlo,
    const unsigned short* __restrict__ khi, const unsigned short* __restrict__ klo,
    const unsigned short* __restrict__ vb, unsigned short* __restrict__ attout)
{
    const int qt = blockIdx.x;
    const int bh = blockIdx.y;
    const int b = bh >> 4;
    const int h = bh & 15;
    const int q0 = qt * 128;
    const int tid = threadIdx.x;
    const int wid = tid >> 6;
    const int lane = tid & 63;
    const int l15 = lane & 15, lhi = lane >> 4;

    const size_t base = (size_t)bh * T_ * D_;
    const unsigned short* Qh = qhi + base;
    const unsigned short* Ql = qlo + base;
    const unsigned short* Kh = khi + base;
    const unsigned short* Kl = klo + base;
    const unsigned short* V = vb + base;

    __shared__ unsigned short Ksh[64][68], Ksl[64][68];  // K tile hi/lo
    __shared__ unsigned short Vts[64][68];               // V^T
    __shared__ unsigned short Ps[128][68];               // P tile

    bf16x8 qfh[2][2], qfl[2][2];
    #pragma unroll
    for (int mt = 0; mt < 2; mt++)
        #pragma unroll
        for (int kk = 0; kk < 2; kk++) {
            size_t off = (size_t)(q0 + wid * 32 + mt * 16 + l15) * D_ + kk * 32 + lhi * 8;
            qfh[mt][kk] = *reinterpret_cast<const bf16x8*>(&Qh[off]);
            qfl[mt][kk] = *reinterpret_cast<const bf16x8*>(&Ql[off]);
        }

    f32x4 accO[2][4];
    float mrow[2][4], lrow[2][4];
    #pragma unroll
    for (int mt = 0; mt < 2; mt++) {
        #pragma unroll
        for (int nt = 0; nt < 4; nt++) accO[mt][nt] = zero4();
        #pragma unroll
        for (int r2 = 0; r2 < 4; r2++) { mrow[mt][r2] = -__builtin_inff(); lrow[mt][r2] = 0.f; }
    }

    const int kvend = q0 + 128;
    for (int kv0 = 0; kv0 < kvend; kv0 += 64) {
        {
            int r = tid >> 2;
            int c0 = (tid & 3) * 16;
            size_t off = (size_t)(kv0 + r) * D_ + c0;
            *reinterpret_cast<u16x8*>(&Ksh[r][c0])     = *reinterpret_cast<const u16x8*>(&Kh[off]);
            *reinterpret_cast<u16x8*>(&Ksh[r][c0 + 8]) = *reinterpret_cast<const u16x8*>(&Kh[off + 8]);
            *reinterpret_cast<u16x8*>(&Ksl[r][c0])     = *reinterpret_cast<const u16x8*>(&Kl[off]);
            *reinterpret_cast<u16x8*>(&Ksl[r][c0 + 8]) = *reinterpret_cast<const u16x8*>(&Kl[off + 8]);
            u16x8 va = *reinterpret_cast<const u16x8*>(&V[off]);
            u16x8 vb2 = *reinterpret_cast<const u16x8*>(&V[off + 8]);
            #pragma unroll
            for (int i = 0; i < 8; i++) { Vts[c0 + i][r] = va[i]; Vts[c0 + 8 + i][r] = vb2[i]; }
        }
        __syncthreads();

        f32x4 s[2][4];
        #pragma unroll
        for (int mt = 0; mt < 2; mt++)
            #pragma unroll
            for (int st = 0; st < 4; st++) s[mt][st] = zero4();
        #pragma unroll
        for (int kk = 0; kk < 2; kk++) {
            bf16x8 kfh[4], kfl[4];
            #pragma unroll
            for (int st = 0; st < 4; st++) {
                kfh[st] = *reinterpret_cast<const bf16x8*>(&Ksh[st * 16 + l15][kk * 32 + lhi * 8]);
                kfl[st] = *reinterpret_cast<const bf16x8*>(&Ksl[st * 16 + l15][kk * 32 + lhi * 8]);
            }
            #pragma unroll
            for (int mt = 0; mt < 2; mt++)
                #pragma unroll
                for (int st = 0; st < 4; st++) {
                    s[mt][st] = __builtin_amdgcn_mfma_f32_16x16x32_bf16(qfh[mt][kk], kfh[st], s[mt][st], 0, 0, 0);
                    s[mt][st] = __builtin_amdgcn_mfma_f32_16x16x32_bf16(qfh[mt][kk], kfl[st], s[mt][st], 0, 0, 0);
                    s[mt][st] = __builtin_amdgcn_mfma_f32_16x16x32_bf16(qfl[mt][kk], kfh[st], s[mt][st], 0, 0, 0);
                }
        }

        #pragma unroll
        for (int mt = 0; mt < 2; mt++) {
            float pm[4];
            #pragma unroll
            for (int r2 = 0; r2 < 4; r2++) pm[r2] = -__builtin_inff();
            #pragma unroll
            for (int st = 0; st < 4; st++) {
                #pragma unroll
                for (int r2 = 0; r2 < 4; r2++) {
                    int grow = q0 + wid * 32 + mt * 16 + lhi * 4 + r2;
                    int gcol = kv0 + st * 16 + l15;
                    float v = s[mt][st][r2] * 8.0f;
                    v = (gcol > grow) ? -__builtin_inff() : v;
                    s[mt][st][r2] = v;
                    pm[r2] = fmaxf(pm[r2], v);
                }
            }
            #pragma unroll
            for (int r2 = 0; r2 < 4; r2++) {
                #pragma unroll
                for (int off = 1; off < 16; off <<= 1)
                    pm[r2] = fmaxf(pm[r2], __shfl_xor(pm[r2], off, 64));
                float newm = fmaxf(mrow[mt][r2], pm[r2]);
                float scale = expf(mrow[mt][r2] - newm);
                mrow[mt][r2] = newm;
                float rs = 0.f;
                #pragma unroll
                for (int st = 0; st < 4; st++) {
                    float p = expf(s[mt][st][r2] - newm);
                    s[mt][st][r2] = p;
                    rs += p;
                }
                #pragma unroll
                for (int off = 1; off < 16; off <<= 1)
                    rs += __shfl_xor(rs, off, 64);
                lrow[mt][r2] = lrow[mt][r2] * scale + rs;
                #pragma unroll
                for (int nt = 0; nt < 4; nt++) accO[mt][nt][r2] *= scale;
            }
        }

        #pragma unroll
        for (int mt = 0; mt < 2; mt++)
            #pragma unroll
            for (int st = 0; st < 4; st++)
                #pragma unroll
                for (int r2 = 0; r2 < 4; r2++) {
                    int lr = wid * 32 + mt * 16 + lhi * 4 + r2;
                    Ps[lr][st * 16 + l15] = f2bf(s[mt][st][r2]);
                }

        #pragma unroll
        for (int step = 0; step < 2; step++) {
            bf16x8 pf[2];
            #pragma unroll
            for (int mt = 0; mt < 2; mt++)
                pf[mt] = *reinterpret_cast<const bf16x8*>(&Ps[wid * 32 + mt * 16 + l15][step * 32 + lhi * 8]);
            #pragma unroll
            for (int nt = 0; nt < 4; nt++) {
                bf16x8 vf = *reinterpret_cast<const bf16x8*>(&Vts[nt * 16 + l15][step * 32 + lhi * 8]);
                #pragma unroll
                for (int mt = 0; mt < 2; mt++)
                    accO[mt][nt] = __builtin_amdgcn_mfma_f32_16x16x32_bf16(pf[mt], vf, accO[mt][nt], 0, 0, 0);
            }
        }
        __syncthreads();
    }

    #pragma unroll
    for (int mt = 0; mt < 2; mt++)
        #pragma unroll
        for (int nt = 0; nt < 4; nt++)
            #pragma unroll
            for (int r2 = 0; r2 < 4; r2++) {
                int t = q0 + wid * 32 + mt * 16 + lhi * 4 + r2;
                int d = nt * 16 + l15;
                float o = accO[mt][nt][r2] / lrow[mt][r2];
                attout[((size_t)b * T_ + t) * (H_ * D_) + h * D_ + d] = f2bf(o);
            }
}

// ---------------------------------------------------------------------------
// Kernel 3: output projection + bias.  grid(64, 8), block 256.
// ---------------------------------------------------------------------------
__global__ __launch_bounds__(256) void proj_kernel(
    const unsigned short* __restrict__ attout, const float* __restrict__ Wp,
    const float* __restrict__ bp, float* __restrict__ out)
{
    const int rt = blockIdx.x;
    const int ct = blockIdx.y;
    const int row0 = rt * 128;
    const int c0 = ct * 128;
    const int tid = threadIdx.x;
    const int wid = tid >> 6;
    const int lane = tid & 63;
    const int l15 = lane & 15, lhi = lane >> 4;

    __shared__ unsigned short As[128][72];
    __shared__ unsigned short WTs[128][72];

    f32x4 acc[2][8];
    #pragma unroll
    for (int mt = 0; mt < 2; mt++)
        #pragma unroll
        for (int nt = 0; nt < 8; nt++) acc[mt][nt] = zero4();

    for (int k0 = 0; k0 < C_; k0 += 64) {
        __syncthreads();
        {
            int r = tid >> 1;
            int cb = (tid & 1) * 32;
            const unsigned short* src = attout + (size_t)(row0 + r) * C_ + k0 + cb;
            #pragma unroll
            for (int i = 0; i < 4; i++)
                *reinterpret_cast<u16x8*>(&As[r][cb + i * 8]) =
                    *reinterpret_cast<const u16x8*>(src + i * 8);
        }
        {
            int j = tid >> 2;
            int cb = (tid & 3) * 32;
            const float* src = Wp + (size_t)(k0 + j) * C_ + c0 + cb;
            #pragma unroll
            for (int i = 0; i < 8; i++) {
                f32x4 v = *reinterpret_cast<const f32x4*>(src + i * 4);
                WTs[cb + i * 4 + 0][j] = f2bf(v[0]);
                WTs[cb + i * 4 + 1][j] = f2bf(v[1]);
                WTs[cb + i * 4 + 2][j] = f2bf(v[2]);
                WTs[cb + i * 4 + 3][j] = f2bf(v[3]);
            }
        }
        __syncthreads();
        #pragma unroll
        for (int kk = 0; kk < 2; kk++) {
            bf16x8 af[2];
            #pragma unroll
            for (int mt = 0; mt < 2; mt++)
                af[mt] = *reinterpret_cast<const bf16x8*>(&As[wid * 32 + mt * 16 + l15][kk * 32 + lhi * 8]);
            #pragma unroll
            for (int nt = 0; nt < 8; nt++) {
                bf16x8 wf = *reinterpret_cast<const bf16x8*>(&WTs[nt * 16 + l15][kk * 32 + lhi * 8]);
                #pragma unroll
                for (int mt = 0; mt < 2; mt++)
                    acc[mt][nt] = __builtin_amdgcn_mfma_f32_16x16x32_bf16(af[mt], wf, acc[mt][nt], 0, 0, 0);
            }
        }
    }

    #pragma unroll
    for (int mt = 0; mt < 2; mt++)
        #pragma unroll
        for (int nt = 0; nt < 8; nt++)
            #pragma unroll
            for (int r2 = 0; r2 < 4; r2++) {
                int row = row0 + wid * 32 + mt * 16 + lhi * 4 + r2;
                int col = c0 + nt * 16 + l15;
                out[(size_t)row * C_ + col] = acc[mt][nt][r2] + bp[col];
            }
}

// ---------------------------------------------------------------------------
extern "C" void kernel_launch(void* const* d_in, const int* in_sizes, int n_in,
                              void* d_out, int out_size, void* d_ws, size_t ws_size,
                              hipStream_t stream) {
    const float* x  = (const float*)d_in[0];
    const float* Wq = (const float*)d_in[1];
    const float* Wk = (const float*)d_in[2];
    const float* Wv = (const float*)d_in[3];
    const float* Wp = (const float*)d_in[4];
    const float* bp = (const float*)d_in[5];
    float* out = (float*)d_out;

    const size_t nqkv = (size_t)B_ * H_ * T_ * D_;   // 8.4M elems
    unsigned short* qhi = (unsigned short*)d_ws;
    unsigned short* qlo = qhi + nqkv;
    unsigned short* khi = qlo + nqkv;
    unsigned short* klo = khi + nqkv;
    unsigned short* vb  = klo + nqkv;
    unsigned short* attout = vb + nqkv;

    qkv_kernel<<<dim3(BT_ / 128, H_), 256, 0, stream>>>(x, Wq, Wk, Wv, qhi, qlo, khi, klo, vb);
    flash_kernel<<<dim3(T_ / 128, B_ * H_), 256, 0, stream>>>(qhi, qlo, khi, klo, vb, attout);
    proj_kernel<<<dim3(BT_ / 128, C_ / 128), 256, 0, stream>>>(attout, Wp, bp, out);
}

// Round 4
// 428.850 us; speedup vs baseline: 1.7847x; 1.7847x over previous
//
#include <hip/hip_runtime.h>

#define B_ 4
#define T_ 2048
#define C_ 1024
#define H_ 16
#define D_ 64

typedef _Float16 f16x8 __attribute__((ext_vector_type(8)));
typedef __fp16 fp16x2 __attribute__((ext_vector_type(2)));
typedef float f32x4 __attribute__((ext_vector_type(4)));
typedef unsigned short u16x8 __attribute__((ext_vector_type(8)));

#define MFMA16 __builtin_amdgcn_mfma_f32_16x16x32_f16
#define SCALE2 11.541560327111707f   /* 8 * log2(e) */

__device__ __forceinline__ unsigned pk2(float a, float b) {
    fp16x2 p = __builtin_amdgcn_cvt_pkrtz(a, b);
    return __builtin_bit_cast(unsigned, p);
}

// ---------------------------------------------------------------------------
// convx: x fp32 -> Xf fp16.  grid 4096, block 256.
// ---------------------------------------------------------------------------
__global__ __launch_bounds__(256) void convx_kernel(const float* __restrict__ x,
                                                    _Float16* __restrict__ Xf) {
    size_t i = ((size_t)blockIdx.x * 256 + threadIdx.x) * 8;
    f32x4 a = *reinterpret_cast<const f32x4*>(x + i);
    f32x4 b = *reinterpret_cast<const f32x4*>(x + i + 4);
    f16x8 o;
    o[0] = (_Float16)a[0]; o[1] = (_Float16)a[1]; o[2] = (_Float16)a[2]; o[3] = (_Float16)a[3];
    o[4] = (_Float16)b[0]; o[5] = (_Float16)b[1]; o[6] = (_Float16)b[2]; o[7] = (_Float16)b[3];
    *reinterpret_cast<f16x8*>(Xf + i) = o;
}

// ---------------------------------------------------------------------------
// convw_qkv: W[h][c][d] fp32 -> Wt[h][d][c] fp16 (transposed).  grid(8,16,3).
// ---------------------------------------------------------------------------
__global__ __launch_bounds__(256) void convw_qkv_kernel(
    const float* __restrict__ Wq, const float* __restrict__ Wk, const float* __restrict__ Wv,
    _Float16* __restrict__ Wqt, _Float16* __restrict__ Wkt, _Float16* __restrict__ Wvt)
{
    __shared__ unsigned short Wl[128][72];
    const int ct = blockIdx.x, h = blockIdx.y, m = blockIdx.z;
    const float* src = (m == 0 ? Wq : (m == 1 ? Wk : Wv)) + ((size_t)h * C_ + ct * 128) * D_;
    _Float16* dst = (m == 0 ? Wqt : (m == 1 ? Wkt : Wvt));
    const int tid = threadIdx.x;
    {
        int r = tid >> 1, half = tid & 1;
        #pragma unroll
        for (int i = 0; i < 8; i++) {
            f32x4 v = *reinterpret_cast<const f32x4*>(src + (size_t)r * D_ + half * 32 + i * 4);
            #pragma unroll
            for (int j = 0; j < 4; j++)
                Wl[r][half * 32 + i * 4 + j] = __builtin_bit_cast(unsigned short, (_Float16)v[j]);
        }
    }
    __syncthreads();
    {
        int d = tid >> 2, seg = tid & 3;
        #pragma unroll
        for (int i = 0; i < 4; i++) {
            u16x8 o;
            #pragma unroll
            for (int j = 0; j < 8; j++) o[j] = Wl[seg * 32 + i * 8 + j][d];
            *reinterpret_cast<u16x8*>((unsigned short*)dst + ((size_t)h * D_ + d) * C_ + ct * 128 + seg * 32 + i * 8) = o;
        }
    }
}

// ---------------------------------------------------------------------------
// convw_p: Wp[k][j] fp32 -> Wpt[j][k] fp16.  grid(16,16).
// ---------------------------------------------------------------------------
__global__ __launch_bounds__(256) void convw_p_kernel(const float* __restrict__ Wp,
                                                      _Float16* __restrict__ Wpt)
{
    __shared__ unsigned short Pl[64][72];
    const int jt = blockIdx.x, kt = blockIdx.y;
    const int tid = threadIdx.x;
    {
        int r = tid >> 2, seg = tid & 3;
        #pragma unroll
        for (int i = 0; i < 4; i++) {
            f32x4 v = *reinterpret_cast<const f32x4*>(Wp + (size_t)(kt * 64 + r) * C_ + jt * 64 + seg * 16 + i * 4);
            #pragma unroll
            for (int j = 0; j < 4; j++)
                Pl[r][seg * 16 + i * 4 + j] = __builtin_bit_cast(unsigned short, (_Float16)v[j]);
        }
    }
    __syncthreads();
    {
        int jj = tid >> 2, kseg = tid & 3;
        #pragma unroll
        for (int i = 0; i < 2; i++) {
            u16x8 o;
            #pragma unroll
            for (int j = 0; j < 8; j++) o[j] = Pl[kseg * 16 + i * 8 + j][jj];
            *reinterpret_cast<u16x8*>((unsigned short*)Wpt + (size_t)(jt * 64 + jj) * C_ + kt * 64 + kseg * 16 + i * 8) = o;
        }
    }
}

// ---------------------------------------------------------------------------
// qkv: LDS-free direct-fragment GEMM.  grid(64,16), block 256 (4 indep waves).
// q,k -> [bh][t][d] fp16;  v -> Vt [bh][d][t] fp16 (via LDS bounce).
// ---------------------------------------------------------------------------
__global__ __launch_bounds__(256) void qkv_kernel(
    const _Float16* __restrict__ Xf,
    const _Float16* __restrict__ Wqt, const _Float16* __restrict__ Wkt,
    const _Float16* __restrict__ Wvt,
    _Float16* __restrict__ Qf, _Float16* __restrict__ Kf, _Float16* __restrict__ Vt)
{
    __shared__ unsigned short Vl[64][136];
    const int rt = blockIdx.x, h = blockIdx.y;
    const int row0 = rt * 128;
    const int tid = threadIdx.x, wid = tid >> 6, lane = tid & 63;
    const int l15 = lane & 15, g = lane >> 4;
    const int rowbase = row0 + wid * 32;

    const _Float16* Wt0 = Wqt + (size_t)h * D_ * C_;
    const _Float16* Wt1 = Wkt + (size_t)h * D_ * C_;
    const _Float16* Wt2 = Wvt + (size_t)h * D_ * C_;

    f32x4 acc[3][2][4];
    #pragma unroll
    for (int m = 0; m < 3; m++)
        #pragma unroll
        for (int mt = 0; mt < 2; mt++)
            #pragma unroll
            for (int nt = 0; nt < 4; nt++) { f32x4 z = {0.f,0.f,0.f,0.f}; acc[m][mt][nt] = z; }

    for (int k0 = 0; k0 < C_; k0 += 32) {
        f16x8 a[2];
        #pragma unroll
        for (int mt = 0; mt < 2; mt++)
            a[mt] = *reinterpret_cast<const f16x8*>(Xf + (size_t)(rowbase + mt * 16 + l15) * C_ + k0 + g * 8);
        #pragma unroll
        for (int nt = 0; nt < 4; nt++) {
            f16x8 w0 = *reinterpret_cast<const f16x8*>(Wt0 + (size_t)(nt * 16 + l15) * C_ + k0 + g * 8);
            f16x8 w1 = *reinterpret_cast<const f16x8*>(Wt1 + (size_t)(nt * 16 + l15) * C_ + k0 + g * 8);
            f16x8 w2 = *reinterpret_cast<const f16x8*>(Wt2 + (size_t)(nt * 16 + l15) * C_ + k0 + g * 8);
            #pragma unroll
            for (int mt = 0; mt < 2; mt++) {
                acc[0][mt][nt] = MFMA16(a[mt], w0, acc[0][mt][nt], 0, 0, 0);
                acc[1][mt][nt] = MFMA16(a[mt], w1, acc[1][mt][nt], 0, 0, 0);
                acc[2][mt][nt] = MFMA16(a[mt], w2, acc[2][mt][nt], 0, 0, 0);
            }
        }
    }

    const int bq = row0 >> 11;
    const int t0 = row0 & (T_ - 1);
    const size_t obase = ((size_t)(bq * H_ + h)) * T_ * D_;
    // q, k: [bh][t][d]
    #pragma unroll
    for (int mt = 0; mt < 2; mt++)
        #pragma unroll
        for (int nt = 0; nt < 4; nt++)
            #pragma unroll
            for (int r = 0; r < 4; r++) {
                int t = t0 + wid * 32 + mt * 16 + g * 4 + r;
                size_t idx = obase + (size_t)t * D_ + nt * 16 + l15;
                Qf[idx] = (_Float16)acc[0][mt][nt][r];
                Kf[idx] = (_Float16)acc[1][mt][nt][r];
            }
    // v: bounce through LDS to transposed layout [bh][d][t]
    #pragma unroll
    for (int mt = 0; mt < 2; mt++)
        #pragma unroll
        for (int nt = 0; nt < 4; nt++) {
            uint2 w;
            w.x = pk2(acc[2][mt][nt][0], acc[2][mt][nt][1]);
            w.y = pk2(acc[2][mt][nt][2], acc[2][mt][nt][3]);
            *reinterpret_cast<uint2*>(&Vl[nt * 16 + l15][wid * 32 + mt * 16 + g * 4]) = w;
        }
    __syncthreads();
    {
        int d = tid >> 2, seg = tid & 3;
        const size_t vbase = ((size_t)(bq * H_ + h) * D_ + d) * T_ + t0 + seg * 32;
        #pragma unroll
        for (int i = 0; i < 4; i++) {
            u16x8 v = *reinterpret_cast<const u16x8*>(&Vl[d][seg * 32 + i * 8]);
            *reinterpret_cast<u16x8*>((unsigned short*)Vt + vbase + i * 8) = v;
        }
    }
}

// ---------------------------------------------------------------------------
// flash: causal attention, swapped QK^T (S^T = K*Q), lane-local softmax,
// barrier-free, fragments direct from global.  grid(64 bh, 16 qt), block 256.
// Each wave owns 32 q-rows independently.
// ---------------------------------------------------------------------------
__global__ __launch_bounds__(256) void flash_kernel(
    const _Float16* __restrict__ Qf, const _Float16* __restrict__ Kf,
    const _Float16* __restrict__ Vt, _Float16* __restrict__ att)
{
    __shared__ __align__(16) unsigned short Pq[4][32][80];
    const int bh = blockIdx.x;
    const int qt = 15 - blockIdx.y;          // heavy tiles dispatch first
    const int bb = bh >> 4, h = bh & 15;
    const int tid = threadIdx.x, wid = tid >> 6, lane = tid & 63;
    const int l15 = lane & 15, g = lane >> 4;
    const int qw = qt * 128 + wid * 32;

    const _Float16* Qb = Qf + (size_t)bh * T_ * D_;
    const _Float16* Kb = Kf + (size_t)bh * T_ * D_;
    const _Float16* Vb = Vt + (size_t)bh * D_ * T_;

    // Q B-fragments (col = q = l15), hoisted
    f16x8 qf[2][2];
    #pragma unroll
    for (int mt = 0; mt < 2; mt++)
        #pragma unroll
        for (int kk = 0; kk < 2; kk++)
            qf[mt][kk] = *reinterpret_cast<const f16x8*>(Qb + (size_t)(qw + mt * 16 + l15) * D_ + kk * 32 + g * 8);

    f32x4 accO[4][2];                         // [nt=d][mt=q], O^T fragments
    #pragma unroll
    for (int nt = 0; nt < 4; nt++)
        #pragma unroll
        for (int mt = 0; mt < 2; mt++) { f32x4 z = {0.f,0.f,0.f,0.f}; accO[nt][mt] = z; }
    float m[2] = { -1e30f, -1e30f };
    float l[2] = { 0.f, 0.f };

    const int ntiles = (qw + 95) >> 6;        // kv tiles of 64 covering kv <= qw+31
    for (int tI = 0; tI < ntiles; ++tI) {
        const int kv0 = tI * 64;
        const bool maskt = (tI == ntiles - 1);

        // K A-fragments (row = kv = l15)
        f16x8 kf[4][2];
        #pragma unroll
        for (int st = 0; st < 4; st++)
            #pragma unroll
            for (int kk = 0; kk < 2; kk++)
                kf[st][kk] = *reinterpret_cast<const f16x8*>(Kb + (size_t)(kv0 + st * 16 + l15) * D_ + kk * 32 + g * 8);

        // S^T = K Q : fragment [st](kv) x [mt](q)
        f32x4 s[4][2];
        #pragma unroll
        for (int st = 0; st < 4; st++)
            #pragma unroll
            for (int mt = 0; mt < 2; mt++) { f32x4 z = {0.f,0.f,0.f,0.f}; s[st][mt] = z; }
        #pragma unroll
        for (int kk = 0; kk < 2; kk++)
            #pragma unroll
            for (int st = 0; st < 4; st++)
                #pragma unroll
                for (int mt = 0; mt < 2; mt++)
                    s[st][mt] = MFMA16(kf[st][kk], qf[mt][kk], s[st][mt], 0, 0, 0);

        // online softmax, lane-local per q-row (q = l15, kv spread over g and regs)
        #pragma unroll
        for (int mt = 0; mt < 2; mt++) {
            const int qrow = qw + mt * 16 + l15;
            float lv[4][4];
            float vmax = -1e30f;
            #pragma unroll
            for (int st = 0; st < 4; st++)
                #pragma unroll
                for (int r = 0; r < 4; r++) {
                    float v = s[st][mt][r] * SCALE2;
                    if (maskt) {
                        int kv = kv0 + st * 16 + g * 4 + r;
                        v = (kv <= qrow) ? v : -1e30f;
                    }
                    lv[st][r] = v;
                    vmax = fmaxf(vmax, v);
                }
            vmax = fmaxf(vmax, __shfl_xor(vmax, 16, 64));
            vmax = fmaxf(vmax, __shfl_xor(vmax, 32, 64));
            float mnew = fmaxf(m[mt], vmax);
            float alpha = exp2f(m[mt] - mnew);
            m[mt] = mnew;
            float rs = 0.f;
            unsigned pw[4][2];
            #pragma unroll
            for (int st = 0; st < 4; st++) {
                float p0 = exp2f(lv[st][0] - mnew);
                float p1 = exp2f(lv[st][1] - mnew);
                float p2 = exp2f(lv[st][2] - mnew);
                float p3 = exp2f(lv[st][3] - mnew);
                rs += (p0 + p1) + (p2 + p3);
                pw[st][0] = pk2(p0, p1);
                pw[st][1] = pk2(p2, p3);
            }
            rs += __shfl_xor(rs, 16, 64);
            rs += __shfl_xor(rs, 32, 64);
            l[mt] = l[mt] * alpha + rs;
            #pragma unroll
            for (int nt = 0; nt < 4; nt++) accO[nt][mt] *= alpha;
            // P^T row (q-local) -> LDS, contiguous kv
            #pragma unroll
            for (int st = 0; st < 4; st++) {
                uint2 w; w.x = pw[st][0]; w.y = pw[st][1];
                *reinterpret_cast<uint2*>(&Pq[wid][mt * 16 + l15][st * 16 + g * 4]) = w;
            }
        }

        // PV: O^T += V^T * P^T
        #pragma unroll
        for (int kk = 0; kk < 2; kk++) {
            f16x8 pb[2];
            #pragma unroll
            for (int mt = 0; mt < 2; mt++)
                pb[mt] = *reinterpret_cast<const f16x8*>(&Pq[wid][mt * 16 + l15][kk * 32 + g * 8]);
            #pragma unroll
            for (int nt = 0; nt < 4; nt++) {
                f16x8 vf = *reinterpret_cast<const f16x8*>(Vb + (size_t)(nt * 16 + l15) * T_ + kv0 + kk * 32 + g * 8);
                #pragma unroll
                for (int mt = 0; mt < 2; mt++)
                    accO[nt][mt] = MFMA16(vf, pb[mt], accO[nt][mt], 0, 0, 0);
            }
        }
    }

    // epilogue: normalize, write att [b][t][h*64+d] fp16
    #pragma unroll
    for (int mt = 0; mt < 2; mt++) {
        float inv = 1.0f / l[mt];
        int t = qw + mt * 16 + l15;
        #pragma unroll
        for (int nt = 0; nt < 4; nt++) {
            f32x4 o = accO[nt][mt] * inv;
            uint2 w;
            w.x = pk2(o[0], o[1]);
            w.y = pk2(o[2], o[3]);
            size_t off = ((size_t)(bb * T_ + t)) * (H_ * D_) + h * D_ + nt * 16 + g * 4;
            *reinterpret_cast<uint2*>((unsigned short*)att + off) = w;
        }
    }
}

// ---------------------------------------------------------------------------
// proj: out = att @ Wp + bp, LDS-free.  grid(64,8), block 256 (4 indep waves).
// ---------------------------------------------------------------------------
__global__ __launch_bounds__(256) void proj_kernel(
    const _Float16* __restrict__ att, const _Float16* __restrict__ Wpt,
    const float* __restrict__ bp, float* __restrict__ out)
{
    const int rt = blockIdx.x, ct = blockIdx.y;
    const int tid = threadIdx.x, wid = tid >> 6, lane = tid & 63;
    const int l15 = lane & 15, g = lane >> 4;
    const int rowbase = rt * 128 + wid * 32;
    const int c0 = ct * 128;

    f32x4 acc[2][8];
    #pragma unroll
    for (int mt = 0; mt < 2; mt++)
        #pragma unroll
        for (int nt = 0; nt < 8; nt++) { f32x4 z = {0.f,0.f,0.f,0.f}; acc[mt][nt] = z; }

    for (int k0 = 0; k0 < C_; k0 += 32) {
        f16x8 a[2];
        #pragma unroll
        for (int mt = 0; mt < 2; mt++)
            a[mt] = *reinterpret_cast<const f16x8*>(att + (size_t)(rowbase + mt * 16 + l15) * C_ + k0 + g * 8);
        #pragma unroll
        for (int nt = 0; nt < 8; nt++) {
            f16x8 w = *reinterpret_cast<const f16x8*>(Wpt + (size_t)(c0 + nt * 16 + l15) * C_ + k0 + g * 8);
            #pragma unroll
            for (int mt = 0; mt < 2; mt++)
                acc[mt][nt] = MFMA16(a[mt], w, acc[mt][nt], 0, 0, 0);
        }
    }

    #pragma unroll
    for (int mt = 0; mt < 2; mt++)
        #pragma unroll
        for (int nt = 0; nt < 8; nt++)
            #pragma unroll
            for (int r = 0; r < 4; r++) {
                int row = rowbase + mt * 16 + g * 4 + r;
                int col = c0 + nt * 16 + l15;
                out[(size_t)row * C_ + col] = acc[mt][nt][r] + bp[col];
            }
}

// ---------------------------------------------------------------------------
extern "C" void kernel_launch(void* const* d_in, const int* in_sizes, int n_in,
                              void* d_out, int out_size, void* d_ws, size_t ws_size,
                              hipStream_t stream) {
    const float* x  = (const float*)d_in[0];
    const float* Wq = (const float*)d_in[1];
    const float* Wk = (const float*)d_in[2];
    const float* Wv = (const float*)d_in[3];
    const float* Wp = (const float*)d_in[4];
    const float* bp = (const float*)d_in[5];
    float* out = (float*)d_out;

    _Float16* Xf  = (_Float16*)d_ws;                 // 8192x1024
    _Float16* Wqt = Xf  + (size_t)8388608;           // 16x64x1024
    _Float16* Wkt = Wqt + (size_t)1048576;
    _Float16* Wvt = Wkt + (size_t)1048576;
    _Float16* Wpt = Wvt + (size_t)1048576;           // 1024x1024 (transposed)
    _Float16* Qf  = Wpt + (size_t)1048576;           // 64x2048x64
    _Float16* Kf  = Qf  + (size_t)8388608;
    _Float16* Vt  = Kf  + (size_t)8388608;           // 64x64x2048 (transposed)
    _Float16* att = Vt  + (size_t)8388608;           // 4x2048x1024
    // total: 88 MB

    convx_kernel<<<4096, 256, 0, stream>>>(x, Xf);
    convw_qkv_kernel<<<dim3(8, 16, 3), 256, 0, stream>>>(Wq, Wk, Wv, Wqt, Wkt, Wvt);
    convw_p_kernel<<<dim3(16, 16), 256, 0, stream>>>(Wp, Wpt);
    qkv_kernel<<<dim3(64, 16), 256, 0, stream>>>(Xf, Wqt, Wkt, Wvt, Qf, Kf, Vt);
    flash_kernel<<<dim3(64, 16), 256, 0, stream>>>(Qf, Kf, Vt, att);
    proj_kernel<<<dim3(64, 8), 256, 0, stream>>>(att, Wpt, bp, out);
}

// Round 5
// 253.143 us; speedup vs baseline: 3.0234x; 1.6941x over previous
//
#include <hip/hip_runtime.h>

#define B_ 4
#define T_ 2048
#define C_ 1024
#define H_ 16
#define D_ 64

typedef _Float16 f16x8 __attribute__((ext_vector_type(8)));
typedef __fp16 fp16x2 __attribute__((ext_vector_type(2)));
typedef float f32x4 __attribute__((ext_vector_type(4)));
typedef unsigned short u16x8 __attribute__((ext_vector_type(8)));

#define MFMA16 __builtin_amdgcn_mfma_f32_16x16x32_f16
#define SCALE2 11.541560327111707f   /* 8 * log2(e) */

__device__ __forceinline__ unsigned pk2(float a, float b) {
    fp16x2 p = __builtin_amdgcn_cvt_pkrtz(a, b);
    return __builtin_bit_cast(unsigned, p);
}

__device__ __forceinline__ void gl_lds16(const _Float16* g, unsigned short* lds) {
    __builtin_amdgcn_global_load_lds(
        (const __attribute__((address_space(1))) unsigned int*)g,
        (__attribute__((address_space(3))) unsigned int*)lds, 16, 0, 0);
}

// ---------------------------------------------------------------------------
// convx: x fp32 -> Xf fp16.  grid 4096, block 256.
// ---------------------------------------------------------------------------
__global__ __launch_bounds__(256) void convx_kernel(const float* __restrict__ x,
                                                    _Float16* __restrict__ Xf) {
    size_t i = ((size_t)blockIdx.x * 256 + threadIdx.x) * 8;
    f32x4 a = *reinterpret_cast<const f32x4*>(x + i);
    f32x4 b = *reinterpret_cast<const f32x4*>(x + i + 4);
    f16x8 o;
    o[0] = (_Float16)a[0]; o[1] = (_Float16)a[1]; o[2] = (_Float16)a[2]; o[3] = (_Float16)a[3];
    o[4] = (_Float16)b[0]; o[5] = (_Float16)b[1]; o[6] = (_Float16)b[2]; o[7] = (_Float16)b[3];
    *reinterpret_cast<f16x8*>(Xf + i) = o;
}

// ---------------------------------------------------------------------------
// convw_qkv: W[h][c][d] fp32 -> Wt[h][d][c] fp16 (transposed).  grid(8,16,3).
// ---------------------------------------------------------------------------
__global__ __launch_bounds__(256) void convw_qkv_kernel(
    const float* __restrict__ Wq, const float* __restrict__ Wk, const float* __restrict__ Wv,
    _Float16* __restrict__ Wqt, _Float16* __restrict__ Wkt, _Float16* __restrict__ Wvt)
{
    __shared__ unsigned short Wl[128][72];
    const int ct = blockIdx.x, h = blockIdx.y, m = blockIdx.z;
    const float* src = (m == 0 ? Wq : (m == 1 ? Wk : Wv)) + ((size_t)h * C_ + ct * 128) * D_;
    _Float16* dst = (m == 0 ? Wqt : (m == 1 ? Wkt : Wvt));
    const int tid = threadIdx.x;
    {
        int r = tid >> 1, half = tid & 1;
        #pragma unroll
        for (int i = 0; i < 8; i++) {
            f32x4 v = *reinterpret_cast<const f32x4*>(src + (size_t)r * D_ + half * 32 + i * 4);
            #pragma unroll
            for (int j = 0; j < 4; j++)
                Wl[r][half * 32 + i * 4 + j] = __builtin_bit_cast(unsigned short, (_Float16)v[j]);
        }
    }
    __syncthreads();
    {
        int d = tid >> 2, seg = tid & 3;
        #pragma unroll
        for (int i = 0; i < 4; i++) {
            u16x8 o;
            #pragma unroll
            for (int j = 0; j < 8; j++) o[j] = Wl[seg * 32 + i * 8 + j][d];
            *reinterpret_cast<u16x8*>((unsigned short*)dst + ((size_t)h * D_ + d) * C_ + ct * 128 + seg * 32 + i * 8) = o;
        }
    }
}

// ---------------------------------------------------------------------------
// convw_p: Wp[k][j] fp32 -> Wpt[j][k] fp16.  grid(16,16).
// ---------------------------------------------------------------------------
__global__ __launch_bounds__(256) void convw_p_kernel(const float* __restrict__ Wp,
                                                      _Float16* __restrict__ Wpt)
{
    __shared__ unsigned short Pl[64][72];
    const int jt = blockIdx.x, kt = blockIdx.y;
    const int tid = threadIdx.x;
    {
        int r = tid >> 2, seg = tid & 3;
        #pragma unroll
        for (int i = 0; i < 4; i++) {
            f32x4 v = *reinterpret_cast<const f32x4*>(Wp + (size_t)(kt * 64 + r) * C_ + jt * 64 + seg * 16 + i * 4);
            #pragma unroll
            for (int j = 0; j < 4; j++)
                Pl[r][seg * 16 + i * 4 + j] = __builtin_bit_cast(unsigned short, (_Float16)v[j]);
        }
    }
    __syncthreads();
    {
        int jj = tid >> 2, kseg = tid & 3;
        #pragma unroll
        for (int i = 0; i < 2; i++) {
            u16x8 o;
            #pragma unroll
            for (int j = 0; j < 8; j++) o[j] = Pl[kseg * 16 + i * 8 + j][jj];
            *reinterpret_cast<u16x8*>((unsigned short*)Wpt + (size_t)(jt * 64 + jj) * C_ + kt * 64 + kseg * 16 + i * 8) = o;
        }
    }
}

// ---------------------------------------------------------------------------
// qkv2: m97-style LDS GEMM.  X[8192x1024] @ Wcat^T[3072x1024].
// grid(64, 24), block 256 (4 waves, 2x2).  128x128 tile, BK=64.
// ct<8 -> q [bh][t][d]; ct<16 -> k; else v transposed [bh][d][t].
// ---------------------------------------------------------------------------
__global__ __launch_bounds__(256) void qkv2_kernel(
    const _Float16* __restrict__ Xf, const _Float16* __restrict__ Wcat,
    _Float16* __restrict__ Qf, _Float16* __restrict__ Kf, _Float16* __restrict__ Vt)
{
    __shared__ unsigned short As[128 * 64];
    __shared__ unsigned short Bs[128 * 64];
    const int rt = blockIdx.x, ct = blockIdx.y;
    const int row0 = rt * 128, n0 = ct * 128;
    const int tid = threadIdx.x, wid = tid >> 6, lane = tid & 63;
    const int l15 = lane & 15, g = lane >> 4;
    const int wr = wid >> 1, wc = wid & 1;
    const int lrow = lane >> 3, lcol = (lane & 7) * 8;   // staging: 8 rows/chunk

    f32x4 acc[4][4];
    #pragma unroll
    for (int mi = 0; mi < 4; mi++)
        #pragma unroll
        for (int ni = 0; ni < 4; ni++) { f32x4 z = {0.f,0.f,0.f,0.f}; acc[mi][ni] = z; }

    for (int k0 = 0; k0 < C_; k0 += 64) {
        __syncthreads();
        #pragma unroll
        for (int i = 0; i < 4; i++) {
            int c = wid * 4 + i;           // chunk 0..15, 8 rows each
            gl_lds16(Xf   + (size_t)(row0 + c * 8 + lrow) * C_ + k0 + lcol, &As[c * 512]);
            gl_lds16(Wcat + (size_t)(n0   + c * 8 + lrow) * C_ + k0 + lcol, &Bs[c * 512]);
        }
        __syncthreads();
        #pragma unroll
        for (int kk = 0; kk < 2; kk++) {
            f16x8 af[4], bf[4];
            #pragma unroll
            for (int mi = 0; mi < 4; mi++)
                af[mi] = *reinterpret_cast<const f16x8*>(&As[(wr * 64 + mi * 16 + l15) * 64 + kk * 32 + g * 8]);
            #pragma unroll
            for (int ni = 0; ni < 4; ni++)
                bf[ni] = *reinterpret_cast<const f16x8*>(&Bs[(wc * 64 + ni * 16 + l15) * 64 + kk * 32 + g * 8]);
            #pragma unroll
            for (int mi = 0; mi < 4; mi++)
                #pragma unroll
                for (int ni = 0; ni < 4; ni++)
                    acc[mi][ni] = MFMA16(af[mi], bf[ni], acc[mi][ni], 0, 0, 0);
        }
    }

    const int n0w = n0 + wc * 64;
    const int h = (n0w >> 6) & 15;
    const int b = row0 >> 11;
    const int t0b = (row0 & (T_ - 1)) + wr * 64;

    if (ct < 16) {
        _Float16* dst = (ct < 8) ? Qf : Kf;
        const size_t hb = ((size_t)(b * H_ + h)) * T_ * D_;
        #pragma unroll
        for (int mi = 0; mi < 4; mi++)
            #pragma unroll
            for (int ni = 0; ni < 4; ni++) {
                int d = ni * 16 + l15;
                #pragma unroll
                for (int r = 0; r < 4; r++) {
                    int t = t0b + mi * 16 + g * 4 + r;
                    dst[hb + (size_t)t * D_ + d] = (_Float16)acc[mi][ni][r];
                }
            }
    } else {
        const size_t vbase = ((size_t)(b * H_ + h)) * D_ * T_;
        #pragma unroll
        for (int mi = 0; mi < 4; mi++)
            #pragma unroll
            for (int ni = 0; ni < 4; ni++) {
                int d = ni * 16 + l15;
                int t = t0b + mi * 16 + g * 4;
                uint2 w;
                w.x = pk2(acc[mi][ni][0], acc[mi][ni][1]);
                w.y = pk2(acc[mi][ni][2], acc[mi][ni][3]);
                *reinterpret_cast<uint2*>((unsigned short*)Vt + vbase + (size_t)d * T_ + t) = w;
            }
    }
}

// ---------------------------------------------------------------------------
// flash: causal attention, swapped QK^T (S^T = K*Q), lane-local softmax,
// barrier-free, fragments direct from global.  grid(64 bh, 16 qt), block 256.
// ---------------------------------------------------------------------------
__global__ __launch_bounds__(256) void flash_kernel(
    const _Float16* __restrict__ Qf, const _Float16* __restrict__ Kf,
    const _Float16* __restrict__ Vt, _Float16* __restrict__ att)
{
    __shared__ __align__(16) unsigned short Pq[4][32][80];
    const int bh = blockIdx.x;
    const int qt = 15 - blockIdx.y;          // heavy tiles dispatch first
    const int bb = bh >> 4, h = bh & 15;
    const int tid = threadIdx.x, wid = tid >> 6, lane = tid & 63;
    const int l15 = lane & 15, g = lane >> 4;
    const int qw = qt * 128 + wid * 32;

    const _Float16* Qb = Qf + (size_t)bh * T_ * D_;
    const _Float16* Kb = Kf + (size_t)bh * T_ * D_;
    const _Float16* Vb = Vt + (size_t)bh * D_ * T_;

    f16x8 qf[2][2];
    #pragma unroll
    for (int mt = 0; mt < 2; mt++)
        #pragma unroll
        for (int kk = 0; kk < 2; kk++)
            qf[mt][kk] = *reinterpret_cast<const f16x8*>(Qb + (size_t)(qw + mt * 16 + l15) * D_ + kk * 32 + g * 8);

    f32x4 accO[4][2];
    #pragma unroll
    for (int nt = 0; nt < 4; nt++)
        #pragma unroll
        for (int mt = 0; mt < 2; mt++) { f32x4 z = {0.f,0.f,0.f,0.f}; accO[nt][mt] = z; }
    float m[2] = { -1e30f, -1e30f };
    float l[2] = { 0.f, 0.f };

    const int ntiles = (qw + 95) >> 6;
    for (int tI = 0; tI < ntiles; ++tI) {
        const int kv0 = tI * 64;
        const bool maskt = (tI == ntiles - 1);

        f16x8 kf[4][2];
        #pragma unroll
        for (int st = 0; st < 4; st++)
            #pragma unroll
            for (int kk = 0; kk < 2; kk++)
                kf[st][kk] = *reinterpret_cast<const f16x8*>(Kb + (size_t)(kv0 + st * 16 + l15) * D_ + kk * 32 + g * 8);

        f32x4 s[4][2];
        #pragma unroll
        for (int st = 0; st < 4; st++)
            #pragma unroll
            for (int mt = 0; mt < 2; mt++) { f32x4 z = {0.f,0.f,0.f,0.f}; s[st][mt] = z; }
        #pragma unroll
        for (int kk = 0; kk < 2; kk++)
            #pragma unroll
            for (int st = 0; st < 4; st++)
                #pragma unroll
                for (int mt = 0; mt < 2; mt++)
                    s[st][mt] = MFMA16(kf[st][kk], qf[mt][kk], s[st][mt], 0, 0, 0);

        #pragma unroll
        for (int mt = 0; mt < 2; mt++) {
            const int qrow = qw + mt * 16 + l15;
            float lv[4][4];
            float vmax = -1e30f;
            #pragma unroll
            for (int st = 0; st < 4; st++)
                #pragma unroll
                for (int r = 0; r < 4; r++) {
                    float v = s[st][mt][r] * SCALE2;
                    if (maskt) {
                        int kv = kv0 + st * 16 + g * 4 + r;
                        v = (kv <= qrow) ? v : -1e30f;
                    }
                    lv[st][r] = v;
                    vmax = fmaxf(vmax, v);
                }
            vmax = fmaxf(vmax, __shfl_xor(vmax, 16, 64));
            vmax = fmaxf(vmax, __shfl_xor(vmax, 32, 64));
            float mnew = fmaxf(m[mt], vmax);
            float alpha = exp2f(m[mt] - mnew);
            m[mt] = mnew;
            float rs = 0.f;
            unsigned pw[4][2];
            #pragma unroll
            for (int st = 0; st < 4; st++) {
                float p0 = exp2f(lv[st][0] - mnew);
                float p1 = exp2f(lv[st][1] - mnew);
                float p2 = exp2f(lv[st][2] - mnew);
                float p3 = exp2f(lv[st][3] - mnew);
                rs += (p0 + p1) + (p2 + p3);
                pw[st][0] = pk2(p0, p1);
                pw[st][1] = pk2(p2, p3);
            }
            rs += __shfl_xor(rs, 16, 64);
            rs += __shfl_xor(rs, 32, 64);
            l[mt] = l[mt] * alpha + rs;
            #pragma unroll
            for (int nt = 0; nt < 4; nt++) accO[nt][mt] *= alpha;
            #pragma unroll
            for (int st = 0; st < 4; st++) {
                uint2 w; w.x = pw[st][0]; w.y = pw[st][1];
                *reinterpret_cast<uint2*>(&Pq[wid][mt * 16 + l15][st * 16 + g * 4]) = w;
            }
        }

        #pragma unroll
        for (int kk = 0; kk < 2; kk++) {
            f16x8 pb[2];
            #pragma unroll
            for (int mt = 0; mt < 2; mt++)
                pb[mt] = *reinterpret_cast<const f16x8*>(&Pq[wid][mt * 16 + l15][kk * 32 + g * 8]);
            #pragma unroll
            for (int nt = 0; nt < 4; nt++) {
                f16x8 vf = *reinterpret_cast<const f16x8*>(Vb + (size_t)(nt * 16 + l15) * T_ + kv0 + kk * 32 + g * 8);
                #pragma unroll
                for (int mt = 0; mt < 2; mt++)
                    accO[nt][mt] = MFMA16(vf, pb[mt], accO[nt][mt], 0, 0, 0);
            }
        }
    }

    #pragma unroll
    for (int mt = 0; mt < 2; mt++) {
        float inv = 1.0f / l[mt];
        int t = qw + mt * 16 + l15;
        #pragma unroll
        for (int nt = 0; nt < 4; nt++) {
            f32x4 o = accO[nt][mt] * inv;
            uint2 w;
            w.x = pk2(o[0], o[1]);
            w.y = pk2(o[2], o[3]);
            size_t off = ((size_t)(bb * T_ + t)) * (H_ * D_) + h * D_ + nt * 16 + g * 4;
            *reinterpret_cast<uint2*>((unsigned short*)att + off) = w;
        }
    }
}

// ---------------------------------------------------------------------------
// proj2: m97-style LDS GEMM.  out = att[8192x1024] @ Wpt^T + bp.
// grid(64, 8), block 256 (4 waves, 2x2).  128x128 tile, BK=64.
// ---------------------------------------------------------------------------
__global__ __launch_bounds__(256) void proj2_kernel(
    const _Float16* __restrict__ att, const _Float16* __restrict__ Wpt,
    const float* __restrict__ bp, float* __restrict__ out)
{
    __shared__ unsigned short As[128 * 64];
    __shared__ unsigned short Bs[128 * 64];
    const int rt = blockIdx.x, ct = blockIdx.y;
    const int row0 = rt * 128, n0 = ct * 128;
    const int tid = threadIdx.x, wid = tid >> 6, lane = tid & 63;
    const int l15 = lane & 15, g = lane >> 4;
    const int wr = wid >> 1, wc = wid & 1;
    const int lrow = lane >> 3, lcol = (lane & 7) * 8;

    f32x4 acc[4][4];
    #pragma unroll
    for (int mi = 0; mi < 4; mi++)
        #pragma unroll
        for (int ni = 0; ni < 4; ni++) { f32x4 z = {0.f,0.f,0.f,0.f}; acc[mi][ni] = z; }

    for (int k0 = 0; k0 < C_; k0 += 64) {
        __syncthreads();
        #pragma unroll
        for (int i = 0; i < 4; i++) {
            int c = wid * 4 + i;
            gl_lds16(att + (size_t)(row0 + c * 8 + lrow) * C_ + k0 + lcol, &As[c * 512]);
            gl_lds16(Wpt + (size_t)(n0   + c * 8 + lrow) * C_ + k0 + lcol, &Bs[c * 512]);
        }
        __syncthreads();
        #pragma unroll
        for (int kk = 0; kk < 2; kk++) {
            f16x8 af[4], bf[4];
            #pragma unroll
            for (int mi = 0; mi < 4; mi++)
                af[mi] = *reinterpret_cast<const f16x8*>(&As[(wr * 64 + mi * 16 + l15) * 64 + kk * 32 + g * 8]);
            #pragma unroll
            for (int ni = 0; ni < 4; ni++)
                bf[ni] = *reinterpret_cast<const f16x8*>(&Bs[(wc * 64 + ni * 16 + l15) * 64 + kk * 32 + g * 8]);
            #pragma unroll
            for (int mi = 0; mi < 4; mi++)
                #pragma unroll
                for (int ni = 0; ni < 4; ni++)
                    acc[mi][ni] = MFMA16(af[mi], bf[ni], acc[mi][ni], 0, 0, 0);
        }
    }

    #pragma unroll
    for (int mi = 0; mi < 4; mi++)
        #pragma unroll
        for (int ni = 0; ni < 4; ni++) {
            int col = n0 + wc * 64 + ni * 16 + l15;
            float bias = bp[col];
            #pragma unroll
            for (int r = 0; r < 4; r++) {
                int row = row0 + wr * 64 + mi * 16 + g * 4 + r;
                out[(size_t)row * C_ + col] = acc[mi][ni][r] + bias;
            }
        }
}

// ---------------------------------------------------------------------------
extern "C" void kernel_launch(void* const* d_in, const int* in_sizes, int n_in,
                              void* d_out, int out_size, void* d_ws, size_t ws_size,
                              hipStream_t stream) {
    const float* x  = (const float*)d_in[0];
    const float* Wq = (const float*)d_in[1];
    const float* Wk = (const float*)d_in[2];
    const float* Wv = (const float*)d_in[3];
    const float* Wp = (const float*)d_in[4];
    const float* bp = (const float*)d_in[5];
    float* out = (float*)d_out;

    _Float16* Xf  = (_Float16*)d_ws;                 // 8192x1024
    _Float16* Wqt = Xf  + (size_t)8388608;           // 16x64x1024  } contiguous =
    _Float16* Wkt = Wqt + (size_t)1048576;           //             } Wcat[3072][1024]
    _Float16* Wvt = Wkt + (size_t)1048576;           //             }
    _Float16* Wpt = Wvt + (size_t)1048576;           // 1024x1024 (transposed)
    _Float16* Qf  = Wpt + (size_t)1048576;           // 64x2048x64
    _Float16* Kf  = Qf  + (size_t)8388608;
    _Float16* Vt  = Kf  + (size_t)8388608;           // 64x64x2048 (transposed)
    _Float16* att = Vt  + (size_t)8388608;           // 4x2048x1024

    convx_kernel<<<4096, 256, 0, stream>>>(x, Xf);
    convw_qkv_kernel<<<dim3(8, 16, 3), 256, 0, stream>>>(Wq, Wk, Wv, Wqt, Wkt, Wvt);
    convw_p_kernel<<<dim3(16, 16), 256, 0, stream>>>(Wp, Wpt);
    qkv2_kernel<<<dim3(64, 24), 256, 0, stream>>>(Xf, Wqt, Qf, Kf, Vt);
    flash_kernel<<<dim3(64, 16), 256, 0, stream>>>(Qf, Kf, Vt, att);
    proj2_kernel<<<dim3(64, 8), 256, 0, stream>>>(att, Wpt, bp, out);
}

// Round 6
// 249.229 us; speedup vs baseline: 3.0709x; 1.0157x over previous
//
#include <hip/hip_runtime.h>

#define B_ 4
#define T_ 2048
#define C_ 1024
#define H_ 16
#define D_ 64

typedef _Float16 f16x8 __attribute__((ext_vector_type(8)));
typedef __fp16 fp16x2 __attribute__((ext_vector_type(2)));
typedef float f32x4 __attribute__((ext_vector_type(4)));
typedef unsigned short u16x8 __attribute__((ext_vector_type(8)));

#define MFMA16 __builtin_amdgcn_mfma_f32_16x16x32_f16
#define SCALE2 11.541560327111707f   /* 8 * log2(e), pre-folded into Q */

__device__ __forceinline__ unsigned pk2(float a, float b) {
    fp16x2 p = __builtin_amdgcn_cvt_pkrtz(a, b);
    return __builtin_bit_cast(unsigned, p);
}

__device__ __forceinline__ void gl_lds16(const _Float16* g, unsigned short* lds) {
    __builtin_amdgcn_global_load_lds(
        (const __attribute__((address_space(1))) unsigned int*)g,
        (__attribute__((address_space(3))) unsigned int*)lds, 16, 0, 0);
}

// ---------------------------------------------------------------------------
// convx: x fp32 -> Xf fp16.  grid 4096, block 256.
// ---------------------------------------------------------------------------
__global__ __launch_bounds__(256) void convx_kernel(const float* __restrict__ x,
                                                    _Float16* __restrict__ Xf) {
    size_t i = ((size_t)blockIdx.x * 256 + threadIdx.x) * 8;
    f32x4 a = *reinterpret_cast<const f32x4*>(x + i);
    f32x4 b = *reinterpret_cast<const f32x4*>(x + i + 4);
    f16x8 o;
    o[0] = (_Float16)a[0]; o[1] = (_Float16)a[1]; o[2] = (_Float16)a[2]; o[3] = (_Float16)a[3];
    o[4] = (_Float16)b[0]; o[5] = (_Float16)b[1]; o[6] = (_Float16)b[2]; o[7] = (_Float16)b[3];
    *reinterpret_cast<f16x8*>(Xf + i) = o;
}

// ---------------------------------------------------------------------------
// convw_qkv: W[h][c][d] fp32 -> Wt[h][d][c] fp16 (transposed).  grid(8,16,3).
// ---------------------------------------------------------------------------
__global__ __launch_bounds__(256) void convw_qkv_kernel(
    const float* __restrict__ Wq, const float* __restrict__ Wk, const float* __restrict__ Wv,
    _Float16* __restrict__ Wqt, _Float16* __restrict__ Wkt, _Float16* __restrict__ Wvt)
{
    __shared__ unsigned short Wl[128][72];
    const int ct = blockIdx.x, h = blockIdx.y, m = blockIdx.z;
    const float* src = (m == 0 ? Wq : (m == 1 ? Wk : Wv)) + ((size_t)h * C_ + ct * 128) * D_;
    _Float16* dst = (m == 0 ? Wqt : (m == 1 ? Wkt : Wvt));
    const int tid = threadIdx.x;
    {
        int r = tid >> 1, half = tid & 1;
        #pragma unroll
        for (int i = 0; i < 8; i++) {
            f32x4 v = *reinterpret_cast<const f32x4*>(src + (size_t)r * D_ + half * 32 + i * 4);
            #pragma unroll
            for (int j = 0; j < 4; j++)
                Wl[r][half * 32 + i * 4 + j] = __builtin_bit_cast(unsigned short, (_Float16)v[j]);
        }
    }
    __syncthreads();
    {
        int d = tid >> 2, seg = tid & 3;
        #pragma unroll
        for (int i = 0; i < 4; i++) {
            u16x8 o;
            #pragma unroll
            for (int j = 0; j < 8; j++) o[j] = Wl[seg * 32 + i * 8 + j][d];
            *reinterpret_cast<u16x8*>((unsigned short*)dst + ((size_t)h * D_ + d) * C_ + ct * 128 + seg * 32 + i * 8) = o;
        }
    }
}

// ---------------------------------------------------------------------------
// convw_p: Wp[k][j] fp32 -> Wpt[j][k] fp16.  grid(16,16).
// ---------------------------------------------------------------------------
__global__ __launch_bounds__(256) void convw_p_kernel(const float* __restrict__ Wp,
                                                      _Float16* __restrict__ Wpt)
{
    __shared__ unsigned short Pl[64][72];
    const int jt = blockIdx.x, kt = blockIdx.y;
    const int tid = threadIdx.x;
    {
        int r = tid >> 2, seg = tid & 3;
        #pragma unroll
        for (int i = 0; i < 4; i++) {
            f32x4 v = *reinterpret_cast<const f32x4*>(Wp + (size_t)(kt * 64 + r) * C_ + jt * 64 + seg * 16 + i * 4);
            #pragma unroll
            for (int j = 0; j < 4; j++)
                Pl[r][seg * 16 + i * 4 + j] = __builtin_bit_cast(unsigned short, (_Float16)v[j]);
        }
    }
    __syncthreads();
    {
        int jj = tid >> 2, kseg = tid & 3;
        #pragma unroll
        for (int i = 0; i < 2; i++) {
            u16x8 o;
            #pragma unroll
            for (int j = 0; j < 8; j++) o[j] = Pl[kseg * 16 + i * 8 + j][jj];
            *reinterpret_cast<u16x8*>((unsigned short*)Wpt + (size_t)(jt * 64 + jj) * C_ + kt * 64 + kseg * 16 + i * 8) = o;
        }
    }
}

// ---------------------------------------------------------------------------
// qkv2: m97-style LDS GEMM.  X[8192x1024] @ Wcat^T[3072x1024].
// grid(64, 24), block 256 (4 waves, 2x2).  128x128 tile, BK=64.
// ct<8 -> q [bh][t][d] (pre-scaled by SCALE2); ct<16 -> k; else v -> [bh][d][t].
// ---------------------------------------------------------------------------
__global__ __launch_bounds__(256) void qkv2_kernel(
    const _Float16* __restrict__ Xf, const _Float16* __restrict__ Wcat,
    _Float16* __restrict__ Qf, _Float16* __restrict__ Kf, _Float16* __restrict__ Vt)
{
    __shared__ unsigned short As[128 * 64];
    __shared__ unsigned short Bs[128 * 64];
    const int rt = blockIdx.x, ct = blockIdx.y;
    const int row0 = rt * 128, n0 = ct * 128;
    const int tid = threadIdx.x, wid = tid >> 6, lane = tid & 63;
    const int l15 = lane & 15, g = lane >> 4;
    const int wr = wid >> 1, wc = wid & 1;
    const int lrow = lane >> 3, lcol = (lane & 7) * 8;

    f32x4 acc[4][4];
    #pragma unroll
    for (int mi = 0; mi < 4; mi++)
        #pragma unroll
        for (int ni = 0; ni < 4; ni++) { f32x4 z = {0.f,0.f,0.f,0.f}; acc[mi][ni] = z; }

    for (int k0 = 0; k0 < C_; k0 += 64) {
        __syncthreads();
        #pragma unroll
        for (int i = 0; i < 4; i++) {
            int c = wid * 4 + i;
            gl_lds16(Xf   + (size_t)(row0 + c * 8 + lrow) * C_ + k0 + lcol, &As[c * 512]);
            gl_lds16(Wcat + (size_t)(n0   + c * 8 + lrow) * C_ + k0 + lcol, &Bs[c * 512]);
        }
        __syncthreads();
        #pragma unroll
        for (int kk = 0; kk < 2; kk++) {
            f16x8 af[4], bf[4];
            #pragma unroll
            for (int mi = 0; mi < 4; mi++)
                af[mi] = *reinterpret_cast<const f16x8*>(&As[(wr * 64 + mi * 16 + l15) * 64 + kk * 32 + g * 8]);
            #pragma unroll
            for (int ni = 0; ni < 4; ni++)
                bf[ni] = *reinterpret_cast<const f16x8*>(&Bs[(wc * 64 + ni * 16 + l15) * 64 + kk * 32 + g * 8]);
            #pragma unroll
            for (int mi = 0; mi < 4; mi++)
                #pragma unroll
                for (int ni = 0; ni < 4; ni++)
                    acc[mi][ni] = MFMA16(af[mi], bf[ni], acc[mi][ni], 0, 0, 0);
        }
    }

    const int n0w = n0 + wc * 64;
    const int h = (n0w >> 6) & 15;
    const int b = row0 >> 11;
    const int t0b = (row0 & (T_ - 1)) + wr * 64;

    if (ct < 16) {
        _Float16* dst = (ct < 8) ? Qf : Kf;
        const float osc = (ct < 8) ? SCALE2 : 1.0f;   // fold softmax scale into Q
        const size_t hb = ((size_t)(b * H_ + h)) * T_ * D_;
        #pragma unroll
        for (int mi = 0; mi < 4; mi++)
            #pragma unroll
            for (int ni = 0; ni < 4; ni++) {
                int d = ni * 16 + l15;
                #pragma unroll
                for (int r = 0; r < 4; r++) {
                    int t = t0b + mi * 16 + g * 4 + r;
                    dst[hb + (size_t)t * D_ + d] = (_Float16)(acc[mi][ni][r] * osc);
                }
            }
    } else {
        const size_t vbase = ((size_t)(b * H_ + h)) * D_ * T_;
        #pragma unroll
        for (int mi = 0; mi < 4; mi++)
            #pragma unroll
            for (int ni = 0; ni < 4; ni++) {
                int d = ni * 16 + l15;
                int t = t0b + mi * 16 + g * 4;
                uint2 w;
                w.x = pk2(acc[mi][ni][0], acc[mi][ni][1]);
                w.y = pk2(acc[mi][ni][2], acc[mi][ni][3]);
                *reinterpret_cast<uint2*>((unsigned short*)Vt + vbase + (size_t)d * T_ + t) = w;
            }
    }
}

// ---------------------------------------------------------------------------
// flash: causal attention, swapped QK^T (S^T = K*Q), lane-local softmax.
// 1 wave per block, 32 q-rows.  grid(64 bh, 64 qseg), block 64.
// Q pre-scaled by 8*log2e; exp via raw v_exp_f32; Pq XOR-swizzled.
// ---------------------------------------------------------------------------
__global__ __launch_bounds__(64) void flash_kernel(
    const _Float16* __restrict__ Qf, const _Float16* __restrict__ Kf,
    const _Float16* __restrict__ Vt, _Float16* __restrict__ att)
{
    __shared__ __align__(16) unsigned short Pq[32][80];
    const int bh = blockIdx.x;
    const int qseg = 63 - blockIdx.y;        // heavy tiles dispatch first
    const int bb = bh >> 4, h = bh & 15;
    const int lane = threadIdx.x & 63;
    const int l15 = lane & 15, g = lane >> 4;
    const int qw = qseg * 32;

    const _Float16* Qb = Qf + (size_t)bh * T_ * D_;
    const _Float16* Kb = Kf + (size_t)bh * T_ * D_;
    const _Float16* Vb = Vt + (size_t)bh * D_ * T_;

    f16x8 qf[2][2];
    #pragma unroll
    for (int mt = 0; mt < 2; mt++)
        #pragma unroll
        for (int kk = 0; kk < 2; kk++)
            qf[mt][kk] = *reinterpret_cast<const f16x8*>(Qb + (size_t)(qw + mt * 16 + l15) * D_ + kk * 32 + g * 8);

    f32x4 accO[4][2];
    #pragma unroll
    for (int nt = 0; nt < 4; nt++)
        #pragma unroll
        for (int mt = 0; mt < 2; mt++) { f32x4 z = {0.f,0.f,0.f,0.f}; accO[nt][mt] = z; }
    float m[2] = { -1e30f, -1e30f };
    float l[2] = { 0.f, 0.f };

    const int ntiles = (qw + 95) >> 6;
    for (int tI = 0; tI < ntiles; ++tI) {
        const int kv0 = tI * 64;
        const bool maskt = (tI == ntiles - 1);

        f16x8 kf[4][2];
        #pragma unroll
        for (int st = 0; st < 4; st++)
            #pragma unroll
            for (int kk = 0; kk < 2; kk++)
                kf[st][kk] = *reinterpret_cast<const f16x8*>(Kb + (size_t)(kv0 + st * 16 + l15) * D_ + kk * 32 + g * 8);

        f32x4 s[4][2];
        #pragma unroll
        for (int st = 0; st < 4; st++)
            #pragma unroll
            for (int mt = 0; mt < 2; mt++) { f32x4 z = {0.f,0.f,0.f,0.f}; s[st][mt] = z; }
        #pragma unroll
        for (int kk = 0; kk < 2; kk++)
            #pragma unroll
            for (int st = 0; st < 4; st++)
                #pragma unroll
                for (int mt = 0; mt < 2; mt++)
                    s[st][mt] = MFMA16(kf[st][kk], qf[mt][kk], s[st][mt], 0, 0, 0);

        #pragma unroll
        for (int mt = 0; mt < 2; mt++) {
            const int r = mt * 16 + l15;           // local P row
            const int qrow = qw + r;
            float lv[4][4];
            float vmax = -1e30f;
            #pragma unroll
            for (int st = 0; st < 4; st++)
                #pragma unroll
                for (int rr = 0; rr < 4; rr++) {
                    float v = s[st][mt][rr];       // scale pre-folded into Q
                    if (maskt) {
                        int kv = kv0 + st * 16 + g * 4 + rr;
                        v = (kv <= qrow) ? v : -1e30f;
                    }
                    lv[st][rr] = v;
                    vmax = fmaxf(vmax, v);
                }
            vmax = fmaxf(vmax, __shfl_xor(vmax, 16, 64));
            vmax = fmaxf(vmax, __shfl_xor(vmax, 32, 64));
            float mnew = fmaxf(m[mt], vmax);
            float alpha = __builtin_amdgcn_exp2f(m[mt] - mnew);
            m[mt] = mnew;
            float rs = 0.f;
            unsigned pw[4][2];
            #pragma unroll
            for (int st = 0; st < 4; st++) {
                float p0 = __builtin_amdgcn_exp2f(lv[st][0] - mnew);
                float p1 = __builtin_amdgcn_exp2f(lv[st][1] - mnew);
                float p2 = __builtin_amdgcn_exp2f(lv[st][2] - mnew);
                float p3 = __builtin_amdgcn_exp2f(lv[st][3] - mnew);
                rs += (p0 + p1) + (p2 + p3);
                pw[st][0] = pk2(p0, p1);
                pw[st][1] = pk2(p2, p3);
            }
            rs += __shfl_xor(rs, 16, 64);
            rs += __shfl_xor(rs, 32, 64);
            l[mt] = l[mt] * alpha + rs;
            #pragma unroll
            for (int nt = 0; nt < 4; nt++) accO[nt][mt] *= alpha;
            // P^T row -> LDS, XOR-swizzled 16B units (kills bank conflicts)
            char* prow = (char*)&Pq[r][0];
            #pragma unroll
            for (int st = 0; st < 4; st++) {
                uint2 w; w.x = pw[st][0]; w.y = pw[st][1];
                *reinterpret_cast<uint2*>(prow + ((st * 32 + g * 8) ^ ((r & 7) << 4))) = w;
            }
        }

        // PV: O^T += V^T * P^T
        #pragma unroll
        for (int kk = 0; kk < 2; kk++) {
            f16x8 pb[2];
            #pragma unroll
            for (int mt = 0; mt < 2; mt++) {
                const int r = mt * 16 + l15;
                pb[mt] = *reinterpret_cast<const f16x8*>(
                    (const char*)&Pq[r][0] + ((kk * 64 + g * 16) ^ ((r & 7) << 4)));
            }
            #pragma unroll
            for (int nt = 0; nt < 4; nt++) {
                f16x8 vf = *reinterpret_cast<const f16x8*>(Vb + (size_t)(nt * 16 + l15) * T_ + kv0 + kk * 32 + g * 8);
                #pragma unroll
                for (int mt = 0; mt < 2; mt++)
                    accO[nt][mt] = MFMA16(vf, pb[mt], accO[nt][mt], 0, 0, 0);
            }
        }
    }

    #pragma unroll
    for (int mt = 0; mt < 2; mt++) {
        float inv = 1.0f / l[mt];
        int t = qw + mt * 16 + l15;
        #pragma unroll
        for (int nt = 0; nt < 4; nt++) {
            f32x4 o = accO[nt][mt] * inv;
            uint2 w;
            w.x = pk2(o[0], o[1]);
            w.y = pk2(o[2], o[3]);
            size_t off = ((size_t)(bb * T_ + t)) * (H_ * D_) + h * D_ + nt * 16 + g * 4;
            *reinterpret_cast<uint2*>((unsigned short*)att + off) = w;
        }
    }
}

// ---------------------------------------------------------------------------
// proj2: m97-style LDS GEMM.  out = att[8192x1024] @ Wpt^T + bp.
// grid(64, 8), block 256 (4 waves, 2x2).  128x128 tile, BK=64.
// ---------------------------------------------------------------------------
__global__ __launch_bounds__(256) void proj2_kernel(
    const _Float16* __restrict__ att, const _Float16* __restrict__ Wpt,
    const float* __restrict__ bp, float* __restrict__ out)
{
    __shared__ unsigned short As[128 * 64];
    __shared__ unsigned short Bs[128 * 64];
    const int rt = blockIdx.x, ct = blockIdx.y;
    const int row0 = rt * 128, n0 = ct * 128;
    const int tid = threadIdx.x, wid = tid >> 6, lane = tid & 63;
    const int l15 = lane & 15, g = lane >> 4;
    const int wr = wid >> 1, wc = wid & 1;
    const int lrow = lane >> 3, lcol = (lane & 7) * 8;

    f32x4 acc[4][4];
    #pragma unroll
    for (int mi = 0; mi < 4; mi++)
        #pragma unroll
        for (int ni = 0; ni < 4; ni++) { f32x4 z = {0.f,0.f,0.f,0.f}; acc[mi][ni] = z; }

    for (int k0 = 0; k0 < C_; k0 += 64) {
        __syncthreads();
        #pragma unroll
        for (int i = 0; i < 4; i++) {
            int c = wid * 4 + i;
            gl_lds16(att + (size_t)(row0 + c * 8 + lrow) * C_ + k0 + lcol, &As[c * 512]);
            gl_lds16(Wpt + (size_t)(n0   + c * 8 + lrow) * C_ + k0 + lcol, &Bs[c * 512]);
        }
        __syncthreads();
        #pragma unroll
        for (int kk = 0; kk < 2; kk++) {
            f16x8 af[4], bf[4];
            #pragma unroll
            for (int mi = 0; mi < 4; mi++)
                af[mi] = *reinterpret_cast<const f16x8*>(&As[(wr * 64 + mi * 16 + l15) * 64 + kk * 32 + g * 8]);
            #pragma unroll
            for (int ni = 0; ni < 4; ni++)
                bf[ni] = *reinterpret_cast<const f16x8*>(&Bs[(wc * 64 + ni * 16 + l15) * 64 + kk * 32 + g * 8]);
            #pragma unroll
            for (int mi = 0; mi < 4; mi++)
                #pragma unroll
                for (int ni = 0; ni < 4; ni++)
                    acc[mi][ni] = MFMA16(af[mi], bf[ni], acc[mi][ni], 0, 0, 0);
        }
    }

    #pragma unroll
    for (int mi = 0; mi < 4; mi++)
        #pragma unroll
        for (int ni = 0; ni < 4; ni++) {
            int col = n0 + wc * 64 + ni * 16 + l15;
            float bias = bp[col];
            #pragma unroll
            for (int r = 0; r < 4; r++) {
                int row = row0 + wr * 64 + mi * 16 + g * 4 + r;
                out[(size_t)row * C_ + col] = acc[mi][ni][r] + bias;
            }
        }
}

// ---------------------------------------------------------------------------
extern "C" void kernel_launch(void* const* d_in, const int* in_sizes, int n_in,
                              void* d_out, int out_size, void* d_ws, size_t ws_size,
                              hipStream_t stream) {
    const float* x  = (const float*)d_in[0];
    const float* Wq = (const float*)d_in[1];
    const float* Wk = (const float*)d_in[2];
    const float* Wv = (const float*)d_in[3];
    const float* Wp = (const float*)d_in[4];
    const float* bp = (const float*)d_in[5];
    float* out = (float*)d_out;

    _Float16* Xf  = (_Float16*)d_ws;                 // 8192x1024
    _Float16* Wqt = Xf  + (size_t)8388608;           // 16x64x1024  } contiguous =
    _Float16* Wkt = Wqt + (size_t)1048576;           //             } Wcat[3072][1024]
    _Float16* Wvt = Wkt + (size_t)1048576;           //             }
    _Float16* Wpt = Wvt + (size_t)1048576;           // 1024x1024 (transposed)
    _Float16* Qf  = Wpt + (size_t)1048576;           // 64x2048x64  (pre-scaled)
    _Float16* Kf  = Qf  + (size_t)8388608;
    _Float16* Vt  = Kf  + (size_t)8388608;           // 64x64x2048 (transposed)
    _Float16* att = Vt  + (size_t)8388608;           // 4x2048x1024

    convx_kernel<<<4096, 256, 0, stream>>>(x, Xf);
    convw_qkv_kernel<<<dim3(8, 16, 3), 256, 0, stream>>>(Wq, Wk, Wv, Wqt, Wkt, Wvt);
    convw_p_kernel<<<dim3(16, 16), 256, 0, stream>>>(Wp, Wpt);
    qkv2_kernel<<<dim3(64, 24), 256, 0, stream>>>(Xf, Wqt, Qf, Kf, Vt);
    flash_kernel<<<dim3(64, 64), 64, 0, stream>>>(Qf, Kf, Vt, att);
    proj2_kernel<<<dim3(64, 8), 256, 0, stream>>>(att, Wpt, bp, out);
}

// Round 7
// 209.276 us; speedup vs baseline: 3.6571x; 1.1909x over previous
//
#include <hip/hip_runtime.h>

#define B_ 4
#define T_ 2048
#define C_ 1024
#define H_ 16
#define D_ 64

typedef _Float16 f16x8 __attribute__((ext_vector_type(8)));
typedef __fp16 fp16x2 __attribute__((ext_vector_type(2)));
typedef float f32x4 __attribute__((ext_vector_type(4)));
typedef unsigned short u16x8 __attribute__((ext_vector_type(8)));

#define MFMA16 __builtin_amdgcn_mfma_f32_16x16x32_f16
#define SCALE2 11.541560327111707f   /* 8 * log2(e), pre-folded into Q */

__device__ __forceinline__ unsigned pk2(float a, float b) {
    fp16x2 p = __builtin_amdgcn_cvt_pkrtz(a, b);
    return __builtin_bit_cast(unsigned, p);
}

__device__ __forceinline__ void gl_lds16(const _Float16* g, unsigned short* lds) {
    __builtin_amdgcn_global_load_lds(
        (const __attribute__((address_space(1))) unsigned int*)g,
        (__attribute__((address_space(3))) unsigned int*)lds, 16, 0, 0);
}

// ---------------------------------------------------------------------------
// convx: x fp32 -> Xf fp16.  grid 4096, block 256.
// ---------------------------------------------------------------------------
__global__ __launch_bounds__(256) void convx_kernel(const float* __restrict__ x,
                                                    _Float16* __restrict__ Xf) {
    size_t i = ((size_t)blockIdx.x * 256 + threadIdx.x) * 8;
    f32x4 a = *reinterpret_cast<const f32x4*>(x + i);
    f32x4 b = *reinterpret_cast<const f32x4*>(x + i + 4);
    f16x8 o;
    o[0] = (_Float16)a[0]; o[1] = (_Float16)a[1]; o[2] = (_Float16)a[2]; o[3] = (_Float16)a[3];
    o[4] = (_Float16)b[0]; o[5] = (_Float16)b[1]; o[6] = (_Float16)b[2]; o[7] = (_Float16)b[3];
    *reinterpret_cast<f16x8*>(Xf + i) = o;
}

// ---------------------------------------------------------------------------
// convw_qkv: W[h][c][d] fp32 -> Wt[h][d][c] fp16 (transposed).  grid(8,16,3).
// ---------------------------------------------------------------------------
__global__ __launch_bounds__(256) void convw_qkv_kernel(
    const float* __restrict__ Wq, const float* __restrict__ Wk, const float* __restrict__ Wv,
    _Float16* __restrict__ Wqt, _Float16* __restrict__ Wkt, _Float16* __restrict__ Wvt)
{
    __shared__ unsigned short Wl[128][72];
    const int ct = blockIdx.x, h = blockIdx.y, m = blockIdx.z;
    const float* src = (m == 0 ? Wq : (m == 1 ? Wk : Wv)) + ((size_t)h * C_ + ct * 128) * D_;
    _Float16* dst = (m == 0 ? Wqt : (m == 1 ? Wkt : Wvt));
    const int tid = threadIdx.x;
    {
        int r = tid >> 1, half = tid & 1;
        #pragma unroll
        for (int i = 0; i < 8; i++) {
            f32x4 v = *reinterpret_cast<const f32x4*>(src + (size_t)r * D_ + half * 32 + i * 4);
            #pragma unroll
            for (int j = 0; j < 4; j++)
                Wl[r][half * 32 + i * 4 + j] = __builtin_bit_cast(unsigned short, (_Float16)v[j]);
        }
    }
    __syncthreads();
    {
        int d = tid >> 2, seg = tid & 3;
        #pragma unroll
        for (int i = 0; i < 4; i++) {
            u16x8 o;
            #pragma unroll
            for (int j = 0; j < 8; j++) o[j] = Wl[seg * 32 + i * 8 + j][d];
            *reinterpret_cast<u16x8*>((unsigned short*)dst + ((size_t)h * D_ + d) * C_ + ct * 128 + seg * 32 + i * 8) = o;
        }
    }
}

// ---------------------------------------------------------------------------
// convw_p: Wp[k][j] fp32 -> Wpt[j][k] fp16.  grid(16,16).
// ---------------------------------------------------------------------------
__global__ __launch_bounds__(256) void convw_p_kernel(const float* __restrict__ Wp,
                                                      _Float16* __restrict__ Wpt)
{
    __shared__ unsigned short Pl[64][72];
    const int jt = blockIdx.x, kt = blockIdx.y;
    const int tid = threadIdx.x;
    {
        int r = tid >> 2, seg = tid & 3;
        #pragma unroll
        for (int i = 0; i < 4; i++) {
            f32x4 v = *reinterpret_cast<const f32x4*>(Wp + (size_t)(kt * 64 + r) * C_ + jt * 64 + seg * 16 + i * 4);
            #pragma unroll
            for (int j = 0; j < 4; j++)
                Pl[r][seg * 16 + i * 4 + j] = __builtin_bit_cast(unsigned short, (_Float16)v[j]);
        }
    }
    __syncthreads();
    {
        int jj = tid >> 2, kseg = tid & 3;
        #pragma unroll
        for (int i = 0; i < 2; i++) {
            u16x8 o;
            #pragma unroll
            for (int j = 0; j < 8; j++) o[j] = Pl[kseg * 16 + i * 8 + j][jj];
            *reinterpret_cast<u16x8*>((unsigned short*)Wpt + (size_t)(jt * 64 + jj) * C_ + kt * 64 + kseg * 16 + i * 8) = o;
        }
    }
}

// ---------------------------------------------------------------------------
// qkv2: m97-style LDS GEMM.  X[8192x1024] @ Wcat^T[3072x1024].
// grid(64, 24), block 256 (4 waves, 2x2).  128x128 tile, BK=64.
// ct<8 -> q [bh][t][d] (pre-scaled by SCALE2); ct<16 -> k; else v -> [bh][d][t].
// ---------------------------------------------------------------------------
__global__ __launch_bounds__(256) void qkv2_kernel(
    const _Float16* __restrict__ Xf, const _Float16* __restrict__ Wcat,
    _Float16* __restrict__ Qf, _Float16* __restrict__ Kf, _Float16* __restrict__ Vt)
{
    __shared__ unsigned short As[128 * 64];
    __shared__ unsigned short Bs[128 * 64];
    const int rt = blockIdx.x, ct = blockIdx.y;
    const int row0 = rt * 128, n0 = ct * 128;
    const int tid = threadIdx.x, wid = tid >> 6, lane = tid & 63;
    const int l15 = lane & 15, g = lane >> 4;
    const int wr = wid >> 1, wc = wid & 1;
    const int lrow = lane >> 3, lcol = (lane & 7) * 8;

    f32x4 acc[4][4];
    #pragma unroll
    for (int mi = 0; mi < 4; mi++)
        #pragma unroll
        for (int ni = 0; ni < 4; ni++) { f32x4 z = {0.f,0.f,0.f,0.f}; acc[mi][ni] = z; }

    for (int k0 = 0; k0 < C_; k0 += 64) {
        __syncthreads();
        #pragma unroll
        for (int i = 0; i < 4; i++) {
            int c = wid * 4 + i;
            gl_lds16(Xf   + (size_t)(row0 + c * 8 + lrow) * C_ + k0 + lcol, &As[c * 512]);
            gl_lds16(Wcat + (size_t)(n0   + c * 8 + lrow) * C_ + k0 + lcol, &Bs[c * 512]);
        }
        __syncthreads();
        #pragma unroll
        for (int kk = 0; kk < 2; kk++) {
            f16x8 af[4], bf[4];
            #pragma unroll
            for (int mi = 0; mi < 4; mi++)
                af[mi] = *reinterpret_cast<const f16x8*>(&As[(wr * 64 + mi * 16 + l15) * 64 + kk * 32 + g * 8]);
            #pragma unroll
            for (int ni = 0; ni < 4; ni++)
                bf[ni] = *reinterpret_cast<const f16x8*>(&Bs[(wc * 64 + ni * 16 + l15) * 64 + kk * 32 + g * 8]);
            #pragma unroll
            for (int mi = 0; mi < 4; mi++)
                #pragma unroll
                for (int ni = 0; ni < 4; ni++)
                    acc[mi][ni] = MFMA16(af[mi], bf[ni], acc[mi][ni], 0, 0, 0);
        }
    }

    const int n0w = n0 + wc * 64;
    const int h = (n0w >> 6) & 15;
    const int b = row0 >> 11;
    const int t0b = (row0 & (T_ - 1)) + wr * 64;

    if (ct < 16) {
        _Float16* dst = (ct < 8) ? Qf : Kf;
        const float osc = (ct < 8) ? SCALE2 : 1.0f;   // fold softmax scale into Q
        const size_t hb = ((size_t)(b * H_ + h)) * T_ * D_;
        #pragma unroll
        for (int mi = 0; mi < 4; mi++)
            #pragma unroll
            for (int ni = 0; ni < 4; ni++) {
                int d = ni * 16 + l15;
                #pragma unroll
                for (int r = 0; r < 4; r++) {
                    int t = t0b + mi * 16 + g * 4 + r;
                    dst[hb + (size_t)t * D_ + d] = (_Float16)(acc[mi][ni][r] * osc);
                }
            }
    } else {
        const size_t vbase = ((size_t)(b * H_ + h)) * D_ * T_;
        #pragma unroll
        for (int mi = 0; mi < 4; mi++)
            #pragma unroll
            for (int ni = 0; ni < 4; ni++) {
                int d = ni * 16 + l15;
                int t = t0b + mi * 16 + g * 4;
                uint2 w;
                w.x = pk2(acc[mi][ni][0], acc[mi][ni][1]);
                w.y = pk2(acc[mi][ni][2], acc[mi][ni][3]);
                *reinterpret_cast<uint2*>((unsigned short*)Vt + vbase + (size_t)d * T_ + t) = w;
            }
    }
}

// ---------------------------------------------------------------------------
// flash: causal attention.  grid(64 bh, 16 qt), block 256 (4 waves).
// K/V tiles double-buffered in LDS via global_load_lds with pre-swizzled
// source (linear DMA dest + XOR-swizzled ds_read => conflict-free).
// Swapped QK^T (S^T = K*Q), lane-local softmax, Q pre-scaled by 8*log2e.
// ---------------------------------------------------------------------------
__global__ __launch_bounds__(256) void flash_kernel(
    const _Float16* __restrict__ Qf, const _Float16* __restrict__ Kf,
    const _Float16* __restrict__ Vt, _Float16* __restrict__ att)
{
    __shared__ __align__(16) unsigned short Ks[2][64 * 64];  // [buf][kv][d] swizzled
    __shared__ __align__(16) unsigned short Vs[2][64 * 64];  // [buf][d][kv] swizzled
    __shared__ __align__(16) unsigned short Ps[4][32 * 64];  // per-wave P^T, swizzled
    const int bh = blockIdx.x;
    const int qt = 15 - (int)blockIdx.y;     // heavy tiles dispatch first
    const int bb = bh >> 4, h = bh & 15;
    const int tid = threadIdx.x, wid = tid >> 6, lane = tid & 63;
    const int l15 = lane & 15, g = lane >> 4;
    const int q0 = qt * 128;
    const int qw = q0 + wid * 32;

    const _Float16* Qb = Qf + (size_t)bh * T_ * D_;
    const _Float16* Kb = Kf + (size_t)bh * T_ * D_;
    const _Float16* Vb = Vt + (size_t)bh * D_ * T_;

    // staging lane constants: 8 lanes per 128B row, pre-swizzled source unit
    const int srow = lane >> 3;                 // row within 8-row chunk
    const int sunit = (lane & 7) ^ srow;        // 16B unit to fetch (inverse swizzle)
    const int r0s = wid * 16;                   // this wave stages rows r0s..r0s+15

    f16x8 qf[2][2];
    #pragma unroll
    for (int mt = 0; mt < 2; mt++)
        #pragma unroll
        for (int kk = 0; kk < 2; kk++)
            qf[mt][kk] = *reinterpret_cast<const f16x8*>(Qb + (size_t)(qw + mt * 16 + l15) * D_ + kk * 32 + g * 8);

    f32x4 accO[4][2];
    #pragma unroll
    for (int nt = 0; nt < 4; nt++)
        #pragma unroll
        for (int mt = 0; mt < 2; mt++) { f32x4 z = {0.f,0.f,0.f,0.f}; accO[nt][mt] = z; }
    float m[2] = { -1e30f, -1e30f };
    float l[2] = { 0.f, 0.f };

    const int myNt = (qw + 95) >> 6;            // tiles this wave computes
    const int ntB  = (q0 + 191) >> 6;           // block max (wave 3)

    // prologue: stage tile 0 into buf 0
    #pragma unroll
    for (int i = 0; i < 2; i++) {
        int row = r0s + i * 8 + srow;
        gl_lds16(Kb + (size_t)row * D_ + sunit * 8, &Ks[0][(r0s + i * 8) * 64]);
        gl_lds16(Vb + (size_t)row * T_ + sunit * 8, &Vs[0][(r0s + i * 8) * 64]);
    }
    __syncthreads();

    int cur = 0;
    for (int tI = 0; tI < ntB; ++tI) {
        const int kv0 = tI * 64;
        // prefetch next tile into the other buffer (hidden under compute)
        if (tI + 1 < ntB) {
            const int kvn = kv0 + 64;
            #pragma unroll
            for (int i = 0; i < 2; i++) {
                int row = r0s + i * 8 + srow;
                gl_lds16(Kb + (size_t)(kvn + row) * D_ + sunit * 8, &Ks[cur ^ 1][(r0s + i * 8) * 64]);
                gl_lds16(Vb + (size_t)row * T_ + kvn + sunit * 8, &Vs[cur ^ 1][(r0s + i * 8) * 64]);
            }
        }

        if (tI < myNt) {
            const bool maskt = (tI == myNt - 1);
            const char* kbase = (const char*)&Ks[cur][0];
            const char* vbase = (const char*)&Vs[cur][0];

            // S^T = K Q
            f32x4 s[4][2];
            #pragma unroll
            for (int st = 0; st < 4; st++)
                #pragma unroll
                for (int mt = 0; mt < 2; mt++) { f32x4 z = {0.f,0.f,0.f,0.f}; s[st][mt] = z; }
            #pragma unroll
            for (int kk = 0; kk < 2; kk++) {
                f16x8 kfr[4];
                #pragma unroll
                for (int st = 0; st < 4; st++) {
                    int row = st * 16 + l15;
                    kfr[st] = *reinterpret_cast<const f16x8*>(
                        kbase + row * 128 + (((kk * 4 + g) ^ (row & 7)) * 16));
                }
                #pragma unroll
                for (int st = 0; st < 4; st++)
                    #pragma unroll
                    for (int mt = 0; mt < 2; mt++)
                        s[st][mt] = MFMA16(kfr[st], qf[mt][kk], s[st][mt], 0, 0, 0);
            }

            // online softmax, lane-local per q-row (q = l15)
            #pragma unroll
            for (int mt = 0; mt < 2; mt++) {
                const int r = mt * 16 + l15;
                const int qrow = qw + r;
                float lv[4][4];
                float vmax = -1e30f;
                #pragma unroll
                for (int st = 0; st < 4; st++)
                    #pragma unroll
                    for (int rr = 0; rr < 4; rr++) {
                        float v = s[st][mt][rr];
                        if (maskt) {
                            int kv = kv0 + st * 16 + g * 4 + rr;
                            v = (kv <= qrow) ? v : -1e30f;
                        }
                        lv[st][rr] = v;
                        vmax = fmaxf(vmax, v);
                    }
                vmax = fmaxf(vmax, __shfl_xor(vmax, 16, 64));
                vmax = fmaxf(vmax, __shfl_xor(vmax, 32, 64));
                float mnew = fmaxf(m[mt], vmax);
                float alpha = __builtin_amdgcn_exp2f(m[mt] - mnew);
                m[mt] = mnew;
                float rs = 0.f;
                unsigned pw[4][2];
                #pragma unroll
                for (int st = 0; st < 4; st++) {
                    float p0 = __builtin_amdgcn_exp2f(lv[st][0] - mnew);
                    float p1 = __builtin_amdgcn_exp2f(lv[st][1] - mnew);
                    float p2 = __builtin_amdgcn_exp2f(lv[st][2] - mnew);
                    float p3 = __builtin_amdgcn_exp2f(lv[st][3] - mnew);
                    rs += (p0 + p1) + (p2 + p3);
                    pw[st][0] = pk2(p0, p1);
                    pw[st][1] = pk2(p2, p3);
                }
                rs += __shfl_xor(rs, 16, 64);
                rs += __shfl_xor(rs, 32, 64);
                l[mt] = l[mt] * alpha + rs;
                #pragma unroll
                for (int nt = 0; nt < 4; nt++) accO[nt][mt] *= alpha;
                char* prow = (char*)&Ps[wid][0] + r * 128;
                #pragma unroll
                for (int st = 0; st < 4; st++) {
                    uint2 w; w.x = pw[st][0]; w.y = pw[st][1];
                    *reinterpret_cast<uint2*>(prow + ((st * 32 + g * 8) ^ ((r & 7) << 4))) = w;
                }
            }

            // PV: O^T += V^T * P^T
            #pragma unroll
            for (int kk = 0; kk < 2; kk++) {
                f16x8 pb[2];
                #pragma unroll
                for (int mt = 0; mt < 2; mt++) {
                    const int r = mt * 16 + l15;
                    pb[mt] = *reinterpret_cast<const f16x8*>(
                        (const char*)&Ps[wid][0] + r * 128 + ((kk * 64 + g * 16) ^ ((r & 7) << 4)));
                }
                #pragma unroll
                for (int nt = 0; nt < 4; nt++) {
                    int row = nt * 16 + l15;
                    f16x8 vf = *reinterpret_cast<const f16x8*>(
                        vbase + row * 128 + (((kk * 4 + g) ^ (row & 7)) * 16));
                    #pragma unroll
                    for (int mt = 0; mt < 2; mt++)
                        accO[nt][mt] = MFMA16(vf, pb[mt], accO[nt][mt], 0, 0, 0);
                }
            }
        }
        __syncthreads();   // drains vmcnt (next tile landed) + all reads of cur done
        cur ^= 1;
    }

    // epilogue: normalize, write att [b][t][h*64+d] fp16
    #pragma unroll
    for (int mt = 0; mt < 2; mt++) {
        float inv = 1.0f / l[mt];
        int t = qw + mt * 16 + l15;
        #pragma unroll
        for (int nt = 0; nt < 4; nt++) {
            f32x4 o = accO[nt][mt] * inv;
            uint2 w;
            w.x = pk2(o[0], o[1]);
            w.y = pk2(o[2], o[3]);
            size_t off = ((size_t)(bb * T_ + t)) * (H_ * D_) + h * D_ + nt * 16 + g * 4;
            *reinterpret_cast<uint2*>((unsigned short*)att + off) = w;
        }
    }
}

// ---------------------------------------------------------------------------
// proj2: m97-style LDS GEMM.  out = att[8192x1024] @ Wpt^T + bp.
// grid(64, 8), block 256 (4 waves, 2x2).  128x128 tile, BK=64.
// ---------------------------------------------------------------------------
__global__ __launch_bounds__(256) void proj2_kernel(
    const _Float16* __restrict__ att, const _Float16* __restrict__ Wpt,
    const float* __restrict__ bp, float* __restrict__ out)
{
    __shared__ unsigned short As[128 * 64];
    __shared__ unsigned short Bs[128 * 64];
    const int rt = blockIdx.x, ct = blockIdx.y;
    const int row0 = rt * 128, n0 = ct * 128;
    const int tid = threadIdx.x, wid = tid >> 6, lane = tid & 63;
    const int l15 = lane & 15, g = lane >> 4;
    const int wr = wid >> 1, wc = wid & 1;
    const int lrow = lane >> 3, lcol = (lane & 7) * 8;

    f32x4 acc[4][4];
    #pragma unroll
    for (int mi = 0; mi < 4; mi++)
        #pragma unroll
        for (int ni = 0; ni < 4; ni++) { f32x4 z = {0.f,0.f,0.f,0.f}; acc[mi][ni] = z; }

    for (int k0 = 0; k0 < C_; k0 += 64) {
        __syncthreads();
        #pragma unroll
        for (int i = 0; i < 4; i++) {
            int c = wid * 4 + i;
            gl_lds16(att + (size_t)(row0 + c * 8 + lrow) * C_ + k0 + lcol, &As[c * 512]);
            gl_lds16(Wpt + (size_t)(n0   + c * 8 + lrow) * C_ + k0 + lcol, &Bs[c * 512]);
        }
        __syncthreads();
        #pragma unroll
        for (int kk = 0; kk < 2; kk++) {
            f16x8 af[4], bf[4];
            #pragma unroll
            for (int mi = 0; mi < 4; mi++)
                af[mi] = *reinterpret_cast<const f16x8*>(&As[(wr * 64 + mi * 16 + l15) * 64 + kk * 32 + g * 8]);
            #pragma unroll
            for (int ni = 0; ni < 4; ni++)
                bf[ni] = *reinterpret_cast<const f16x8*>(&Bs[(wc * 64 + ni * 16 + l15) * 64 + kk * 32 + g * 8]);
            #pragma unroll
            for (int mi = 0; mi < 4; mi++)
                #pragma unroll
                for (int ni = 0; ni < 4; ni++)
                    acc[mi][ni] = MFMA16(af[mi], bf[ni], acc[mi][ni], 0, 0, 0);
        }
    }

    #pragma unroll
    for (int mi = 0; mi < 4; mi++)
        #pragma unroll
        for (int ni = 0; ni < 4; ni++) {
            int col = n0 + wc * 64 + ni * 16 + l15;
            float bias = bp[col];
            #pragma unroll
            for (int r = 0; r < 4; r++) {
                int row = row0 + wr * 64 + mi * 16 + g * 4 + r;
                out[(size_t)row * C_ + col] = acc[mi][ni][r] + bias;
            }
        }
}

// ---------------------------------------------------------------------------
extern "C" void kernel_launch(void* const* d_in, const int* in_sizes, int n_in,
                              void* d_out, int out_size, void* d_ws, size_t ws_size,
                              hipStream_t stream) {
    const float* x  = (const float*)d_in[0];
    const float* Wq = (const float*)d_in[1];
    const float* Wk = (const float*)d_in[2];
    const float* Wv = (const float*)d_in[3];
    const float* Wp = (const float*)d_in[4];
    const float* bp = (const float*)d_in[5];
    float* out = (float*)d_out;

    _Float16* Xf  = (_Float16*)d_ws;                 // 8192x1024
    _Float16* Wqt = Xf  + (size_t)8388608;           // 16x64x1024  } contiguous =
    _Float16* Wkt = Wqt + (size_t)1048576;           //             } Wcat[3072][1024]
    _Float16* Wvt = Wkt + (size_t)1048576;           //             }
    _Float16* Wpt = Wvt + (size_t)1048576;           // 1024x1024 (transposed)
    _Float16* Qf  = Wpt + (size_t)1048576;           // 64x2048x64  (pre-scaled)
    _Float16* Kf  = Qf  + (size_t)8388608;
    _Float16* Vt  = Kf  + (size_t)8388608;           // 64x64x2048 (transposed)
    _Float16* att = Vt  + (size_t)8388608;           // 4x2048x1024

    convx_kernel<<<4096, 256, 0, stream>>>(x, Xf);
    convw_qkv_kernel<<<dim3(8, 16, 3), 256, 0, stream>>>(Wq, Wk, Wv, Wqt, Wkt, Wvt);
    convw_p_kernel<<<dim3(16, 16), 256, 0, stream>>>(Wp, Wpt);
    qkv2_kernel<<<dim3(64, 24), 256, 0, stream>>>(Xf, Wqt, Qf, Kf, Vt);
    flash_kernel<<<dim3(64, 16), 256, 0, stream>>>(Qf, Kf, Vt, att);
    proj2_kernel<<<dim3(64, 8), 256, 0, stream>>>(att, Wpt, bp, out);
}